// Round 6
// baseline (313.322 us; speedup 1.0000x reference)
//
#include <hip/hip_runtime.h>
#include <hip/hip_bf16.h>

// PrunedKVAttention: B=2,T=2048,E=1024,H=16,D=64,K_KEEP=391,RECENCY=64
// Round 6: T3-minimal double-buffered pipelines in all MFMA kernels,
// V-block single-product fast path, XCD-affinity grid transposes.

#define TT 2048
#define EE 1024
#define HH 16
#define DD 64
#define KKEEP 391
#define REC 64
#define NBH 32
#define QSCALE 0.125f
#define KPAD 448

typedef short bf16x8 __attribute__((ext_vector_type(8)));
typedef _Float16 f16x8 __attribute__((ext_vector_type(8)));
typedef float f32x4 __attribute__((ext_vector_type(4)));

static __device__ inline unsigned short bf_rn(float x) {
  unsigned u = __float_as_uint(x);
  unsigned r = u + 0x7fffu + ((u >> 16) & 1u);
  return (unsigned short)(r >> 16);
}
static __device__ inline float bf_up(unsigned short h) {
  return __uint_as_float((unsigned)h << 16);
}
static __device__ inline unsigned pkf16(float a, float b) {
  union { _Float16 h[2]; unsigned u; } t;
  t.h[0] = (_Float16)a; t.h[1] = (_Float16)b; return t.u;
}
// async global->LDS, 16B per lane; LDS dest = wave-uniform base + lane*16
static __device__ inline void glds16(const void* g, void* l) {
  __builtin_amdgcn_global_load_lds(
      (const __attribute__((address_space(1))) void*)g,
      (__attribute__((address_space(3))) void*)l, 16, 0, 0);
}

// ---------------- split f32 -> (hi, lo) bf16 planes ----------------
__global__ __launch_bounds__(256) void split_kernel(
    const float* __restrict__ src, unsigned short* __restrict__ ho,
    unsigned short* __restrict__ lo_, int n)
{
  int i = (blockIdx.x * 256 + threadIdx.x) * 4;
  const int stride = gridDim.x * 1024;
  for (; i < n; i += stride) {
    float4 v = *reinterpret_cast<const float4*>(&src[i]);
    ushort4 hh, ll;
    float f;
    hh.x = bf_rn(v.x); f = bf_up(hh.x); ll.x = bf_rn(v.x - f);
    hh.y = bf_rn(v.y); f = bf_up(hh.y); ll.y = bf_rn(v.y - f);
    hh.z = bf_rn(v.z); f = bf_up(hh.z); ll.z = bf_rn(v.z - f);
    hh.w = bf_rn(v.w); f = bf_up(hh.w); ll.w = bf_rn(v.w - f);
    *reinterpret_cast<ushort4*>(&ho[i]) = hh;
    *reinterpret_cast<ushort4*>(&lo_[i]) = ll;
  }
}

// ---------------- MFMA GEMM (NT): C[M,N] = A[M,K]*B[N,K]^T ----------------
// Double-buffered glds staging (stage-next-then-compute, 1 barrier/K-step).
// V-column blocks (mode 1, blockIdx.x>=16): single product, half staging.
__global__ __launch_bounds__(256) void gemm_bf16s_nt(
    const unsigned short* __restrict__ Ah, const unsigned short* __restrict__ Al,
    const unsigned short* __restrict__ Bh, const unsigned short* __restrict__ Bl,
    float* __restrict__ Cc, unsigned short* __restrict__ Qho, unsigned short* __restrict__ Qlo,
    unsigned short* __restrict__ Kho, unsigned short* __restrict__ Klo,
    float* __restrict__ Vo, int M, int N, int Kd, int mode)
{
  __shared__ __align__(16) unsigned short Ahs[2][128 * 32];
  __shared__ __align__(16) unsigned short Als[2][128 * 32];
  __shared__ __align__(16) unsigned short Bhs[2][128 * 32];
  __shared__ __align__(16) unsigned short Bls[2][128 * 32];
  const int tid = threadIdx.x;
  const int m0 = blockIdx.y * 128, n0 = blockIdx.x * 128;
  const int w = tid >> 6, lane = tid & 63;
  const int wm = w >> 1, wn = w & 1;
  const int l15 = lane & 15, l4 = lane >> 4;
  const bool vblk = (mode == 1) && (blockIdx.x >= 16);

  // per-lane staging constants (2 segments/wave/plane)
  size_t gA[2], gB[2]; int ldso[2];
#pragma unroll
  for (int s = 0; s < 2; s++) {
    int seg = w * 2 + s;
    int r = seg * 16 + (lane >> 2);
    int kb = (lane & 3) ^ ((r >> 1) & 3);
    gA[s] = (size_t)(m0 + r) * Kd + kb * 8;
    gB[s] = (size_t)(n0 + r) * Kd + kb * 8;
    ldso[s] = seg * 512;
  }

  auto STAGE = [&](int bb, int k0) {
#pragma unroll
    for (int s = 0; s < 2; s++) {
      glds16(&Ah[gA[s] + k0], &Ahs[bb][ldso[s]]);
      glds16(&Bh[gB[s] + k0], &Bhs[bb][ldso[s]]);
      if (!vblk) {
        glds16(&Al[gA[s] + k0], &Als[bb][ldso[s]]);
        glds16(&Bl[gB[s] + k0], &Bls[bb][ldso[s]]);
      }
    }
  };

  f32x4 acc[4][4] = {};

  STAGE(0, 0);
  __syncthreads();
  int cur = 0;
  for (int k0 = 0; k0 < Kd; k0 += 32) {
    if (k0 + 32 < Kd) STAGE(cur ^ 1, k0 + 32);
    bf16x8 ah[4], al[4], bh[4], bl[4];
#pragma unroll
    for (int i = 0; i < 4; i++) {
      int ar = wm * 64 + i * 16 + l15;
      int aoff = ar * 32 + ((l4 ^ ((ar >> 1) & 3)) * 8);
      ah[i] = *reinterpret_cast<const bf16x8*>(&Ahs[cur][aoff]);
      int br = wn * 64 + i * 16 + l15;
      int boff = br * 32 + ((l4 ^ ((br >> 1) & 3)) * 8);
      bh[i] = *reinterpret_cast<const bf16x8*>(&Bhs[cur][boff]);
      if (!vblk) {
        al[i] = *reinterpret_cast<const bf16x8*>(&Als[cur][aoff]);
        bl[i] = *reinterpret_cast<const bf16x8*>(&Bls[cur][boff]);
      }
    }
#pragma unroll
    for (int i = 0; i < 4; i++)
#pragma unroll
      for (int j = 0; j < 4; j++) {
        acc[i][j] = __builtin_amdgcn_mfma_f32_16x16x32_bf16(ah[i], bh[j], acc[i][j], 0, 0, 0);
        if (!vblk) {
          acc[i][j] = __builtin_amdgcn_mfma_f32_16x16x32_bf16(ah[i], bl[j], acc[i][j], 0, 0, 0);
          acc[i][j] = __builtin_amdgcn_mfma_f32_16x16x32_bf16(al[i], bh[j], acc[i][j], 0, 0, 0);
        }
      }
    __syncthreads();
    cur ^= 1;
  }

  if (mode == 0) {
#pragma unroll
    for (int i = 0; i < 4; i++) {
      int mrow0 = m0 + wm * 64 + i * 16 + l4 * 4;
#pragma unroll
      for (int j = 0; j < 4; j++) {
        int ncol = n0 + wn * 64 + j * 16 + l15;
#pragma unroll
        for (int r = 0; r < 4; r++)
          Cc[(size_t)(mrow0 + r) * N + ncol] = acc[i][j][r];
      }
    }
  } else {
#pragma unroll
    for (int j = 0; j < 4; j++) {
      int n = n0 + wn * 64 + j * 16 + l15;
      int p = n >> 10, rr = n & 1023;
      int h = rr >> 6, d0 = rr & 63;
#pragma unroll
      for (int i = 0; i < 4; i++) {
        int mrow0 = m0 + wm * 64 + i * 16 + l4 * 4;
#pragma unroll
        for (int r = 0; r < 4; r++) {
          int m = mrow0 + r;
          int b = m >> 11, t = m & 2047;
          size_t idx = ((size_t)((b * HH + h) * TT + t)) * DD + d0;
          float v = acc[i][j][r];
          if (p == 2) {
            Vo[idx] = v;
          } else {
            unsigned short hi_ = bf_rn(v);
            unsigned short lo2 = bf_rn(v - bf_up(hi_));
            if (p == 0) { Qho[idx] = hi_; Qlo[idx] = lo2; }
            else        { Kho[idx] = hi_; Klo[idx] = lo2; }
          }
        }
      }
    }
  }
}

// ---------------- Importance (MFMA): causal softmax column sums ----------------
// grid (bh=32, pair=8) -> all blocks of one bh on one XCD. K chunks dbuf'd.
__global__ __launch_bounds__(512) void importance3_kernel(
    const unsigned short* __restrict__ Qh, const unsigned short* __restrict__ Ql,
    const unsigned short* __restrict__ Kh, const unsigned short* __restrict__ Kl,
    float* __restrict__ part)
{
  const int pairid = blockIdx.y, bh = blockIdx.x;
  const int tid = threadIdx.x;
  const int w = tid >> 6, lane = tid & 63;
  const int wm = w >> 1, wn = w & 1;
  const int l15 = lane & 15, l4 = lane >> 4;
  __shared__ __align__(16) unsigned short Qhs[128 * 64];       // 16 KB
  __shared__ __align__(16) unsigned short Qls[128 * 64];       // 16 KB
  __shared__ __align__(16) unsigned short Khs[2][128 * 64];    // 32 KB
  __shared__ __align__(16) unsigned short Kls[2][128 * 64];    // 32 KB
  __shared__ float csw[8 * 128];                               // 4 KB
  __shared__ float rsb[2 * 128];                               // 1 KB

  // per-lane K staging constants (2 segs/wave/plane, 16 segs total)
  int krow[2], kkb[2], klds[2];
#pragma unroll
  for (int s = 0; s < 2; s++) {
    int seg = w * 2 + s;
    int r = seg * 8 + (lane >> 3);
    int k8 = lane & 7;
    krow[s] = r; kkb[s] = k8 ^ (r & 7); klds[s] = seg * 512;
  }
  auto STAGEK = [&](int bb, int ci) {
#pragma unroll
    for (int s = 0; s < 2; s++) {
      size_t ga = ((size_t)(bh * TT + ci * 128 + krow[s])) * DD + kkb[s] * 8;
      glds16(&Kh[ga], &Khs[bb][klds[s]]);
      glds16(&Kl[ga], &Kls[bb][klds[s]]);
    }
  };

  for (int half = 0; half < 2; half++) {
    const int rt = half ? (15 - pairid) : pairid;
    const int row0 = rt * 128;
    const int nch = rt + 1;
    __syncthreads();
    // stage Q tile (128 rows x 64 dims), swizzled chunk layout
#pragma unroll
    for (int cc = 0; cc < 2; cc++) {
      int c = cc * 512 + tid;
      int r = c >> 3, k8 = c & 7;
      int so = r * 64 + ((k8 ^ (r & 7)) * 8);
      size_t ga = ((size_t)(bh * TT + row0 + r)) * DD + k8 * 8;
      *reinterpret_cast<bf16x8*>(&Qhs[so]) = *reinterpret_cast<const bf16x8*>(&Qh[ga]);
      *reinterpret_cast<bf16x8*>(&Qls[so]) = *reinterpret_cast<const bf16x8*>(&Ql[ga]);
    }

    float rsum[2][4];
#pragma unroll
    for (int i = 0; i < 2; i++)
#pragma unroll
      for (int r = 0; r < 4; r++) rsum[i][r] = 0.f;
    float invl[2][4];

    for (int sweep = 0; sweep < 2; sweep++) {
      STAGEK(0, 0);
      __syncthreads();      // Q writes visible + chunk 0 loaded
      int cur = 0;
      for (int ci = 0; ci < nch; ci++) {
        if (ci + 1 < nch) STAGEK(cur ^ 1, ci + 1);
        f32x4 acc[2][4] = {};
#pragma unroll
        for (int ks = 0; ks < 2; ks++) {
          bf16x8 ah[2], al_[2];
#pragma unroll
          for (int i = 0; i < 2; i++) {
            int ar = wm * 32 + i * 16 + l15;
            int off = ar * 64 + (((ks * 4 + l4) ^ (ar & 7)) * 8);
            ah[i]  = *reinterpret_cast<const bf16x8*>(&Qhs[off]);
            al_[i] = *reinterpret_cast<const bf16x8*>(&Qls[off]);
          }
#pragma unroll
          for (int j = 0; j < 4; j++) {
            int br = wn * 64 + j * 16 + l15;
            int off = br * 64 + (((ks * 4 + l4) ^ (br & 7)) * 8);
            bf16x8 bh_ = *reinterpret_cast<const bf16x8*>(&Khs[cur][off]);
            bf16x8 bl_ = *reinterpret_cast<const bf16x8*>(&Kls[cur][off]);
#pragma unroll
            for (int i = 0; i < 2; i++) {
              acc[i][j] = __builtin_amdgcn_mfma_f32_16x16x32_bf16(ah[i], bh_, acc[i][j], 0, 0, 0);
              acc[i][j] = __builtin_amdgcn_mfma_f32_16x16x32_bf16(ah[i], bl_, acc[i][j], 0, 0, 0);
              acc[i][j] = __builtin_amdgcn_mfma_f32_16x16x32_bf16(al_[i], bh_, acc[i][j], 0, 0, 0);
            }
          }
        }
        const bool diag = (ci == rt);
        if (sweep == 0) {
#pragma unroll
          for (int i = 0; i < 2; i++)
#pragma unroll
            for (int r = 0; r < 4; r++) {
              int row = row0 + wm * 32 + i * 16 + l4 * 4 + r;
              float s = 0.f;
#pragma unroll
              for (int j = 0; j < 4; j++) {
                int key = ci * 128 + wn * 64 + j * 16 + l15;
                float p = __expf(acc[i][j][r] * QSCALE);
                if (diag && key > row) p = 0.f;
                s += p;
              }
              rsum[i][r] += s;
            }
          __syncthreads();    // fence before Khs[cur^1] overwrite next iter
        } else {
          float cp[4];
#pragma unroll
          for (int j = 0; j < 4; j++) cp[j] = 0.f;
#pragma unroll
          for (int i = 0; i < 2; i++)
#pragma unroll
            for (int r = 0; r < 4; r++) {
              int row = row0 + wm * 32 + i * 16 + l4 * 4 + r;
              float il = invl[i][r];
#pragma unroll
              for (int j = 0; j < 4; j++) {
                int key = ci * 128 + wn * 64 + j * 16 + l15;
                float p = __expf(acc[i][j][r] * QSCALE) * il;
                if (diag && key > row) p = 0.f;
                cp[j] += p;
              }
            }
#pragma unroll
          for (int j = 0; j < 4; j++) {
            float v = cp[j];
            v += __shfl_xor(v, 16); v += __shfl_xor(v, 32);
            cp[j] = v;
          }
          if (l4 == 0) {
#pragma unroll
            for (int j = 0; j < 4; j++)
              csw[w * 128 + wn * 64 + j * 16 + l15] = cp[j];
          }
          __syncthreads();
          if (tid < 128) {
            int wnc = tid >> 6;
            float s = csw[(0 * 2 + wnc) * 128 + tid] + csw[(1 * 2 + wnc) * 128 + tid] +
                      csw[(2 * 2 + wnc) * 128 + tid] + csw[(3 * 2 + wnc) * 128 + tid];
            size_t pi = ((size_t)(bh * 8 + pairid)) * 2048 + ci * 128 + tid;
            bool wr = (half == 0) || (ci > pairid);
            part[pi] = wr ? s : (part[pi] + s);
          }
          __syncthreads();
        }
        cur ^= 1;
      }
      if (sweep == 0) {
#pragma unroll
        for (int i = 0; i < 2; i++)
#pragma unroll
          for (int r = 0; r < 4; r++) {
            float v = rsum[i][r];
            v += __shfl_xor(v, 1); v += __shfl_xor(v, 2);
            v += __shfl_xor(v, 4); v += __shfl_xor(v, 8);
            rsum[i][r] = v;
          }
        if (l15 == 0) {
#pragma unroll
          for (int i = 0; i < 2; i++)
#pragma unroll
            for (int r = 0; r < 4; r++)
              rsb[wn * 128 + wm * 32 + i * 16 + l4 * 4 + r] = rsum[i][r];
        }
        __syncthreads();
#pragma unroll
        for (int i = 0; i < 2; i++)
#pragma unroll
          for (int r = 0; r < 4; r++) {
            int rl = wm * 32 + i * 16 + l4 * 4 + r;
            invl[i][r] = 1.0f / (rsb[rl] + rsb[128 + rl]);
          }
      }
    }
  }
}

// ---------------- Top-K select + gather (K f16, V f16-transposed) ----------------
__global__ __launch_bounds__(256) void topk_gather_kernel(
    const float* __restrict__ part,
    const unsigned short* __restrict__ Kh, const unsigned short* __restrict__ Kl,
    const float* __restrict__ V,
    unsigned short* __restrict__ Kf, unsigned short* __restrict__ Vt)
{
  const int bh = blockIdx.x, tid = threadIdx.x;
  const int lane = tid & 63, w = tid >> 6;
  __shared__ int redi[4];
  __shared__ int stot;
  __shared__ int base[256];
  __shared__ int idxb[KKEEP];
  unsigned u[8];
#pragma unroll
  for (int k = 0; k < 8; k++) {
    int e = tid * 8 + k;
    float s = 0.f;
#pragma unroll
    for (int p = 0; p < 8; p++)
      if (e < (16 - p) * 128) s += part[((size_t)(bh * 8 + p)) * 2048 + e];
    float v = (e >= TT - REC) ? 3.0e3f : s;
    u[k] = __float_as_uint(v);
  }
  unsigned lo = 0u, hi = 0x7f800000u;
  for (int it = 0; it < 31; it++) {
    unsigned mid = lo + ((hi - lo + 1) >> 1);
    int c = 0;
#pragma unroll
    for (int k = 0; k < 8; k++) c += (u[k] >= mid) ? 1 : 0;
#pragma unroll
    for (int off = 1; off <= 32; off <<= 1) c += __shfl_xor(c, off);
    if (lane == 0) redi[w] = c;
    __syncthreads();
    int tot = redi[0] + redi[1] + redi[2] + redi[3];
    if (tot >= KKEEP) lo = mid; else hi = mid - 1;
    __syncthreads();
  }
  const unsigned vstar = lo;
  int cgt = 0, ceq = 0;
#pragma unroll
  for (int k = 0; k < 8; k++) { cgt += (u[k] > vstar) ? 1 : 0; ceq += (u[k] == vstar) ? 1 : 0; }
  base[tid] = cgt; __syncthreads();
  if (tid == 0) {
    int run = 0;
    for (int i = 0; i < 256; i++) { int t = base[i]; base[i] = run; run += t; }
    stot = run;
  }
  __syncthreads();
  int off1 = base[tid];
#pragma unroll
  for (int k = 0; k < 8; k++)
    if (u[k] > vstar) idxb[off1++] = tid * 8 + k;
  __syncthreads();
  base[tid] = ceq; __syncthreads();
  if (tid == 0) {
    int run = 0;
    for (int i = 0; i < 256; i++) { int t = base[i]; base[i] = run; run += t; }
  }
  __syncthreads();
  int off2 = stot + base[tid];
#pragma unroll
  for (int k = 0; k < 8; k++)
    if (u[k] == vstar) { if (off2 < KKEEP) idxb[off2] = tid * 8 + k; off2++; }
  __syncthreads();
  // K -> f16 plane [bh][KPAD][64], zero-padded
  for (int f = tid; f < KPAD * 8; f += 256) {
    int kk = f >> 3, c8 = f & 7;
    union { _Float16 h[8]; uint4 v; } o;
#pragma unroll
    for (int j = 0; j < 8; j++) o.h[j] = (_Float16)0.f;
    if (kk < KKEEP) {
      int sr = idxb[kk];
      bf16x8 hv = *reinterpret_cast<const bf16x8*>(&Kh[((size_t)(bh * TT + sr)) * DD + c8 * 8]);
      bf16x8 lv = *reinterpret_cast<const bf16x8*>(&Kl[((size_t)(bh * TT + sr)) * DD + c8 * 8]);
#pragma unroll
      for (int j = 0; j < 8; j++)
        o.h[j] = (_Float16)(bf_up((unsigned short)hv[j]) + bf_up((unsigned short)lv[j]));
    }
    *reinterpret_cast<uint4*>(&Kf[((size_t)(bh * KPAD) + kk) * DD + c8 * 8]) = o.v;
  }
  // V -> f16 transposed plane [bh][64][KPAD], zero-padded
  for (int f = tid; f < KPAD * 8; f += 256) {
    int kk = f >> 3, d8 = f & 7;
    float vv[8];
#pragma unroll
    for (int j = 0; j < 8; j++) vv[j] = 0.f;
    if (kk < KKEEP) {
      int sr = idxb[kk];
      float4 a = *reinterpret_cast<const float4*>(&V[((size_t)(bh * TT + sr)) * DD + d8 * 8]);
      float4 b = *reinterpret_cast<const float4*>(&V[((size_t)(bh * TT + sr)) * DD + d8 * 8 + 4]);
      vv[0] = a.x; vv[1] = a.y; vv[2] = a.z; vv[3] = a.w;
      vv[4] = b.x; vv[5] = b.y; vv[6] = b.z; vv[7] = b.w;
    }
#pragma unroll
    for (int j = 0; j < 8; j++) {
      union { _Float16 h; unsigned short s; } t;
      t.h = (_Float16)vv[j];
      Vt[((size_t)(bh * DD) + d8 * 8 + j) * KPAD + kk] = t.s;
    }
  }
}

// ---------------- Pass-2 attention: f16 MFMA, swapped QK^T ----------------
// grid (bh=32, rt=32) for XCD affinity; K/V chunks double-buffered.
__global__ __launch_bounds__(256) void attn3_kernel(
    const unsigned short* __restrict__ Qh, const unsigned short* __restrict__ Ql,
    const unsigned short* __restrict__ Kf, const unsigned short* __restrict__ Vt,
    unsigned short* __restrict__ AOh, unsigned short* __restrict__ AOl)
{
  const int rt = blockIdx.y, bh = blockIdx.x;
  const int tid = threadIdx.x;
  const int w = tid >> 6, lane = tid & 63;
  const int l15 = lane & 15, l4 = lane >> 4;
  __shared__ __align__(16) unsigned short Qs[64 * 64];      // 8 KB
  __shared__ __align__(16) unsigned short Ks[2][64 * 64];   // 16 KB
  __shared__ __align__(16) unsigned short Vs[2][64 * 64];   // 16 KB
  __shared__ float LDSo[4][64][16];                         // 16 KB
  const int row0 = rt * 64;

  // per-lane staging constants for K/Vt (2 segs/wave/plane)
  int srow[2], skb[2], slds[2];
#pragma unroll
  for (int s = 0; s < 2; s++) {
    int seg = w * 2 + s;
    int r = seg * 8 + (lane >> 3);
    int k8 = lane & 7;
    srow[s] = r; skb[s] = k8 ^ (r & 7); slds[s] = seg * 512;
  }
  auto STAGEA = [&](int bb, int ci) {
#pragma unroll
    for (int s = 0; s < 2; s++) {
      glds16(&Kf[((size_t)(bh * KPAD) + ci * 64 + srow[s]) * DD + skb[s] * 8], &Ks[bb][slds[s]]);
      glds16(&Vt[((size_t)(bh * DD) + srow[s]) * KPAD + ci * 64 + skb[s] * 8], &Vs[bb][slds[s]]);
    }
  };

  // stage Q (f16) from split-bf16 planes
#pragma unroll
  for (int it = 0; it < 2; it++) {
    int idx = it * 256 + tid;
    int r = idx >> 3, k8 = idx & 7;
    size_t ga = ((size_t)(bh * TT + row0 + r)) * DD + k8 * 8;
    bf16x8 hv = *reinterpret_cast<const bf16x8*>(&Qh[ga]);
    bf16x8 lv = *reinterpret_cast<const bf16x8*>(&Ql[ga]);
    union { _Float16 h[8]; uint4 v; } q16;
#pragma unroll
    for (int j = 0; j < 8; j++)
      q16.h[j] = (_Float16)(bf_up((unsigned short)hv[j]) + bf_up((unsigned short)lv[j]));
    *reinterpret_cast<uint4*>(&Qs[r * 64 + ((k8 ^ (r & 7)) * 8)]) = q16.v;
  }
  STAGEA(0, 0);
  __syncthreads();
  // hoist Q B-fragments (wave's 16 q rows)
  f16x8 bq[2];
#pragma unroll
  for (int ks = 0; ks < 2; ks++) {
    int br = w * 16 + l15;
    bq[ks] = *reinterpret_cast<const f16x8*>(&Qs[br * 64 + (((ks * 4 + l4) ^ (br & 7)) * 8)]);
  }

  f32x4 acc_o[4] = {};
  float rsum = 0.f;
  int cur = 0;

  for (int ci = 0; ci < 7; ci++) {
    if (ci + 1 < 7) STAGEA(cur ^ 1, ci + 1);
    // QK^T swapped: C[key][q]
    f32x4 accs[4] = {};
#pragma unroll
    for (int ks = 0; ks < 2; ks++) {
#pragma unroll
      for (int i = 0; i < 4; i++) {
        int kr = i * 16 + l15;
        f16x8 af = *reinterpret_cast<const f16x8*>(&Ks[cur][kr * 64 + (((ks * 4 + l4) ^ (kr & 7)) * 8)]);
        accs[i] = __builtin_amdgcn_mfma_f32_16x16x32_f16(af, bq[ks], accs[i], 0, 0, 0);
      }
    }
    float p[4][4];
#pragma unroll
    for (int i = 0; i < 4; i++)
#pragma unroll
      for (int r = 0; r < 4; r++) {
        int gk = ci * 64 + i * 16 + l4 * 4 + r;
        float pp = __expf(accs[i][r] * QSCALE);
        if (gk >= KKEEP) pp = 0.f;
        p[i][r] = pp;
        rsum += pp;
      }
    unsigned pkU[4][2];
#pragma unroll
    for (int i = 0; i < 4; i++) {
      pkU[i][0] = pkf16(p[i][0], p[i][1]);
      pkU[i][1] = pkf16(p[i][2], p[i][3]);
    }
#pragma unroll
    for (int ks = 0; ks < 2; ks++) {
      union { f16x8 h; unsigned u[4]; } bp;
#pragma unroll
      for (int wp = 0; wp < 4; wp++) {
        int src = ((l4 & 1) * 2 + (wp >> 1)) * 16 + l15;
        unsigned v0 = (unsigned)__shfl((int)pkU[ks * 2][wp & 1], src);
        unsigned v1 = (unsigned)__shfl((int)pkU[ks * 2 + 1][wp & 1], src);
        bp.u[wp] = (l4 & 2) ? v1 : v0;
      }
#pragma unroll
      for (int i = 0; i < 4; i++) {
        int dr = i * 16 + l15;
        f16x8 av = *reinterpret_cast<const f16x8*>(&Vs[cur][dr * 64 + (((ks * 4 + l4) ^ (dr & 7)) * 8)]);
        acc_o[i] = __builtin_amdgcn_mfma_f32_16x16x32_f16(av, bp.h, acc_o[i], 0, 0, 0);
      }
    }
    __syncthreads();
    cur ^= 1;
  }
  // normalize and transpose via LDS
  rsum += __shfl_xor(rsum, 16);
  rsum += __shfl_xor(rsum, 32);
  float inv = 1.0f / rsum;
#pragma unroll
  for (int i = 0; i < 4; i++)
#pragma unroll
    for (int r = 0; r < 4; r++)
      LDSo[w][i * 16 + l4 * 4 + r][l15] = acc_o[i][r] * inv;
  __syncthreads();
  const int b = bh >> 4, h = bh & 15;
#pragma unroll
  for (int uu = 0; uu < 2; uu++) {
    int u = uu * 64 + lane;
    int q = u >> 3, dc = u & 7;
    int row = row0 + w * 16 + q;
    union { unsigned short s[8]; uint4 v; } sh, sl;
#pragma unroll
    for (int j = 0; j < 8; j++) {
      float v = LDSo[w][dc * 8 + j][q];
      unsigned short hh = bf_rn(v);
      sh.s[j] = hh;
      sl.s[j] = bf_rn(v - bf_up(hh));
    }
    size_t addr = ((size_t)(b * TT + row)) * EE + h * DD + dc * 8;
    *reinterpret_cast<uint4*>(&AOh[addr]) = sh.v;
    *reinterpret_cast<uint4*>(&AOl[addr]) = sl.v;
  }
}

extern "C" void kernel_launch(void* const* d_in, const int* in_sizes, int n_in,
                              void* d_out, int out_size, void* d_ws, size_t ws_size,
                              hipStream_t stream)
{
  const float* x     = (const float*)d_in[0];
  const float* Wattn = (const float*)d_in[1];
  const float* Wproj = (const float*)d_in[2];
  float* out = (float*)d_out;
  float* ws  = (float*)d_ws;

  const size_t SZQ = (size_t)NBH * TT * DD;            // 4,194,304 elements
  const size_t SZK = (size_t)NBH * KPAD * DD;          // 917,504
  float* Vb   = ws;                                    // f32 V
  float* part = Vb + SZQ;                              // 524,288 f
  unsigned short* Kf  = (unsigned short*)(part + (size_t)NBH * 8 * TT);
  unsigned short* Vt  = Kf + SZK;
  unsigned short* Qhp = Vt + SZK;
  unsigned short* Qlp = Qhp + SZQ;
  unsigned short* Khp = Qlp + SZQ;
  unsigned short* Klp = Khp + SZQ;
  unsigned short* xh  = Klp + SZQ;                     // x splits (dead after QKV)
  unsigned short* xl  = xh + (size_t)4096 * 1024;
  unsigned short* Wh  = xl + (size_t)4096 * 1024;      // W_attn splits
  unsigned short* Wl  = Wh + (size_t)3072 * 1024;
  unsigned short* AOh = xh;                            // alias
  unsigned short* AOl = xl;
  unsigned short* Ph  = Wh;                            // alias (after QKV GEMM)
  unsigned short* Pl  = Ph + (size_t)1024 * 1024;

  const size_t needB =
      ((size_t)SZQ + (size_t)NBH * 8 * TT) * 4 +
      ((size_t)2 * SZK + (size_t)4 * SZQ + (size_t)2 * 4096 * 1024 + (size_t)2 * 3072 * 1024) * 2;
  if (ws_size < needB) return;   // ~85.5 MB

  // 0) split x, W_attn into bf16 hi/lo planes
  split_kernel<<<512, 256, 0, stream>>>(x, xh, xl, 4096 * 1024);
  split_kernel<<<512, 256, 0, stream>>>(Wattn, Wh, Wl, 3072 * 1024);
  // 1) QKV projection (MFMA): Q,K -> split planes; V -> f32 (V blocks 1-product)
  gemm_bf16s_nt<<<dim3(24, 32), 256, 0, stream>>>(xh, xl, Wh, Wl, nullptr,
                                                  Qhp, Qlp, Khp, Klp, Vb, 4096, 3072, 1024, 1);
  // 1b) split W_proj (aliases W_attn splits; stream-ordered after QKV GEMM)
  split_kernel<<<512, 256, 0, stream>>>(Wproj, Ph, Pl, 1024 * 1024);
  // 2) causal softmax column sums (MFMA, dbuf, XCD-affine grid)
  importance3_kernel<<<dim3(NBH, 8), 512, 0, stream>>>(Qhp, Qlp, Khp, Klp, part);
  // 3) exact top-391 + gather (K f16 plane, V f16 transposed, zero-padded)
  topk_gather_kernel<<<NBH, 256, 0, stream>>>(part, Khp, Klp, Vb, Kf, Vt);
  // 4) pruned-key attention (f16 MFMA, dbuf, XCD-affine grid)
  attn3_kernel<<<dim3(NBH, 32), 256, 0, stream>>>(Qhp, Qlp, Kf, Vt, AOh, AOl);
  // 5) output projection (MFMA)
  gemm_bf16s_nt<<<dim3(8, 32), 256, 0, stream>>>(AOh, AOl, Ph, Pl, out,
                                                 nullptr, nullptr, nullptr, nullptr, nullptr,
                                                 4096, 1024, 1024, 0);
}

// Round 7
// 265.033 us; speedup vs baseline: 1.1822x; 1.1822x over previous
//
#include <hip/hip_runtime.h>
#include <hip/hip_bf16.h>

// PrunedKVAttention: B=2,T=2048,E=1024,H=16,D=64,K_KEEP=391,RECENCY=64
// Round 7: counted-vmcnt pipelines (raw s_barrier, never vmcnt(0) mid-loop)
// in both GEMMs, importance, and attn. Q-frag hoist in importance.
// Math order identical to round 6 -> absmax canary 4.8828e-4.

#define TT 2048
#define EE 1024
#define HH 16
#define DD 64
#define KKEEP 391
#define REC 64
#define NBH 32
#define QSCALE 0.125f
#define KPAD 448

typedef short bf16x8 __attribute__((ext_vector_type(8)));
typedef _Float16 f16x8 __attribute__((ext_vector_type(8)));
typedef float f32x4 __attribute__((ext_vector_type(4)));

#define WAIT_VM(N) asm volatile("s_waitcnt vmcnt(" #N ")" ::: "memory")
#define WAIT_LGKM0 asm volatile("s_waitcnt lgkmcnt(0)" ::: "memory")
#define BAR() __builtin_amdgcn_s_barrier()

static __device__ inline unsigned short bf_rn(float x) {
  unsigned u = __float_as_uint(x);
  unsigned r = u + 0x7fffu + ((u >> 16) & 1u);
  return (unsigned short)(r >> 16);
}
static __device__ inline float bf_up(unsigned short h) {
  return __uint_as_float((unsigned)h << 16);
}
static __device__ inline unsigned pkf16(float a, float b) {
  union { _Float16 h[2]; unsigned u; } t;
  t.h[0] = (_Float16)a; t.h[1] = (_Float16)b; return t.u;
}
// async global->LDS, 16B per lane; LDS dest = wave-uniform base + lane*16
static __device__ inline void glds16(const void* g, void* l) {
  __builtin_amdgcn_global_load_lds(
      (const __attribute__((address_space(1))) void*)g,
      (__attribute__((address_space(3))) void*)l, 16, 0, 0);
}

// ---------------- split f32 -> (hi, lo) bf16 planes ----------------
static __device__ inline void split4(const float* __restrict__ src,
                                     unsigned short* __restrict__ ho,
                                     unsigned short* __restrict__ lo_, int i)
{
  float4 v = *reinterpret_cast<const float4*>(&src[i]);
  ushort4 hh, ll;
  float f;
  hh.x = bf_rn(v.x); f = bf_up(hh.x); ll.x = bf_rn(v.x - f);
  hh.y = bf_rn(v.y); f = bf_up(hh.y); ll.y = bf_rn(v.y - f);
  hh.z = bf_rn(v.z); f = bf_up(hh.z); ll.z = bf_rn(v.z - f);
  hh.w = bf_rn(v.w); f = bf_up(hh.w); ll.w = bf_rn(v.w - f);
  *reinterpret_cast<ushort4*>(&ho[i]) = hh;
  *reinterpret_cast<ushort4*>(&lo_[i]) = ll;
}

__global__ __launch_bounds__(256) void split_kernel(
    const float* __restrict__ src, unsigned short* __restrict__ ho,
    unsigned short* __restrict__ lo_, int n)
{
  int i = (blockIdx.x * 256 + threadIdx.x) * 4;
  const int stride = gridDim.x * 1024;
  for (; i < n; i += stride) split4(src, ho, lo_, i);
}

// merged x + W_attn split
__global__ __launch_bounds__(256) void split2_kernel(
    const float* __restrict__ x, const float* __restrict__ wa,
    unsigned short* __restrict__ xh, unsigned short* __restrict__ xl,
    unsigned short* __restrict__ wh, unsigned short* __restrict__ wl)
{
  const int n1 = 4096 * 1024, n2 = 3072 * 1024;
  int i = (blockIdx.x * 256 + threadIdx.x) * 4;
  const int stride = gridDim.x * 1024;
  for (; i < n1 + n2; i += stride) {
    if (i < n1) split4(x, xh, xl, i);
    else        split4(wa, wh, wl, i - n1);
  }
}

// ---------------- MFMA GEMM (NT), counted-vmcnt 2-deep pipeline ----------------
// VB: single-product V-column blocks. MODE 0: plain C. MODE 1: QKV scatter.
template<bool VB, int MODE>
__global__ __launch_bounds__(256) void gemm_pipe(
    const unsigned short* __restrict__ Ah, const unsigned short* __restrict__ Al,
    const unsigned short* __restrict__ Bh, const unsigned short* __restrict__ Bl,
    float* __restrict__ Cc, unsigned short* __restrict__ Qho, unsigned short* __restrict__ Qlo,
    unsigned short* __restrict__ Kho, unsigned short* __restrict__ Klo,
    float* __restrict__ Vo, int M, int N, int Kd, int nOff)
{
  __shared__ __align__(16) unsigned short Ahs[2][128 * 32];
  __shared__ __align__(16) unsigned short Bhs[2][128 * 32];
  __shared__ __align__(16) unsigned short Als[VB ? 1 : 2][128 * 32];
  __shared__ __align__(16) unsigned short Bls[VB ? 1 : 2][128 * 32];
  const int tid = threadIdx.x;
  const int m0 = blockIdx.y * 128, n0 = nOff + blockIdx.x * 128;
  const int w = tid >> 6, lane = tid & 63;
  const int wm = w >> 1, wn = w & 1;
  const int l15 = lane & 15, l4 = lane >> 4;

  size_t gA[2], gB[2]; int ldso[2];
#pragma unroll
  for (int s = 0; s < 2; s++) {
    int seg = w * 2 + s;
    int r = seg * 16 + (lane >> 2);
    int kb = (lane & 3) ^ ((r >> 1) & 3);
    gA[s] = (size_t)(m0 + r) * Kd + kb * 8;
    gB[s] = (size_t)(n0 + r) * Kd + kb * 8;
    ldso[s] = seg * 512;
  }
  auto STAGE = [&](int bb, int k0) {
#pragma unroll
    for (int s = 0; s < 2; s++) {
      glds16(&Ah[gA[s] + k0], &Ahs[bb][ldso[s]]);
      glds16(&Bh[gB[s] + k0], &Bhs[bb][ldso[s]]);
      if (!VB) {
        glds16(&Al[gA[s] + k0], &Als[bb][ldso[s]]);
        glds16(&Bl[gB[s] + k0], &Bls[bb][ldso[s]]);
      }
    }
  };

  f32x4 acc[4][4] = {};

  STAGE(0, 0);
  STAGE(1, 32);
  int cur = 0;
  for (int k0 = 0; k0 < Kd; k0 += 32) {
    if (k0 + 32 < Kd) { if (VB) WAIT_VM(4); else WAIT_VM(8); }
    else WAIT_VM(0);
    BAR();
    bf16x8 ah[4], al[4], bh[4], bl[4];
#pragma unroll
    for (int i = 0; i < 4; i++) {
      int ar = wm * 64 + i * 16 + l15;
      int aoff = ar * 32 + ((l4 ^ ((ar >> 1) & 3)) * 8);
      ah[i] = *reinterpret_cast<const bf16x8*>(&Ahs[cur][aoff]);
      int br = wn * 64 + i * 16 + l15;
      int boff = br * 32 + ((l4 ^ ((br >> 1) & 3)) * 8);
      bh[i] = *reinterpret_cast<const bf16x8*>(&Bhs[cur][boff]);
      if (!VB) {
        al[i] = *reinterpret_cast<const bf16x8*>(&Als[cur][aoff]);
        bl[i] = *reinterpret_cast<const bf16x8*>(&Bls[cur][boff]);
      }
    }
#pragma unroll
    for (int i = 0; i < 4; i++)
#pragma unroll
      for (int j = 0; j < 4; j++) {
        acc[i][j] = __builtin_amdgcn_mfma_f32_16x16x32_bf16(ah[i], bh[j], acc[i][j], 0, 0, 0);
        if (!VB) {
          acc[i][j] = __builtin_amdgcn_mfma_f32_16x16x32_bf16(ah[i], bl[j], acc[i][j], 0, 0, 0);
          acc[i][j] = __builtin_amdgcn_mfma_f32_16x16x32_bf16(al[i], bh[j], acc[i][j], 0, 0, 0);
        }
      }
    WAIT_LGKM0;
    BAR();
    if (k0 + 64 < Kd) STAGE(cur, k0 + 64);
    cur ^= 1;
  }

  if (MODE == 0) {
#pragma unroll
    for (int i = 0; i < 4; i++) {
      int mrow0 = m0 + wm * 64 + i * 16 + l4 * 4;
#pragma unroll
      for (int j = 0; j < 4; j++) {
        int ncol = n0 + wn * 64 + j * 16 + l15;
#pragma unroll
        for (int r = 0; r < 4; r++)
          Cc[(size_t)(mrow0 + r) * N + ncol] = acc[i][j][r];
      }
    }
  } else if (VB) {
    // V-only columns
#pragma unroll
    for (int j = 0; j < 4; j++) {
      int n = n0 + wn * 64 + j * 16 + l15;
      int rr = n & 1023;
      int h = rr >> 6, d0 = rr & 63;
#pragma unroll
      for (int i = 0; i < 4; i++) {
        int mrow0 = m0 + wm * 64 + i * 16 + l4 * 4;
#pragma unroll
        for (int r = 0; r < 4; r++) {
          int m = mrow0 + r;
          int b = m >> 11, t = m & 2047;
          Vo[((size_t)((b * HH + h) * TT + t)) * DD + d0] = acc[i][j][r];
        }
      }
    }
  } else {
    // Q/K columns -> split-bf16 planes
#pragma unroll
    for (int j = 0; j < 4; j++) {
      int n = n0 + wn * 64 + j * 16 + l15;
      int p = n >> 10, rr = n & 1023;
      int h = rr >> 6, d0 = rr & 63;
#pragma unroll
      for (int i = 0; i < 4; i++) {
        int mrow0 = m0 + wm * 64 + i * 16 + l4 * 4;
#pragma unroll
        for (int r = 0; r < 4; r++) {
          int m = mrow0 + r;
          int b = m >> 11, t = m & 2047;
          size_t idx = ((size_t)((b * HH + h) * TT + t)) * DD + d0;
          float v = acc[i][j][r];
          unsigned short hi_ = bf_rn(v);
          unsigned short lo2 = bf_rn(v - bf_up(hi_));
          if (p == 0) { Qho[idx] = hi_; Qlo[idx] = lo2; }
          else        { Kho[idx] = hi_; Klo[idx] = lo2; }
        }
      }
    }
  }
}

// ---------------- Importance (MFMA): counted pipeline + Q-frag hoist ----------------
__global__ __launch_bounds__(512) void importance4_kernel(
    const unsigned short* __restrict__ Qh, const unsigned short* __restrict__ Ql,
    const unsigned short* __restrict__ Kh, const unsigned short* __restrict__ Kl,
    float* __restrict__ part)
{
  const int pairid = blockIdx.y, bh = blockIdx.x;
  const int tid = threadIdx.x;
  const int w = tid >> 6, lane = tid & 63;
  const int wm = w >> 1, wn = w & 1;
  const int l15 = lane & 15, l4 = lane >> 4;
  __shared__ __align__(16) unsigned short Qhs[128 * 64];
  __shared__ __align__(16) unsigned short Qls[128 * 64];
  __shared__ __align__(16) unsigned short Khs[2][128 * 64];
  __shared__ __align__(16) unsigned short Kls[2][128 * 64];
  __shared__ float csw[8 * 128];
  __shared__ float rsb[2 * 128];

  int krow[2], kkb[2], klds[2];
#pragma unroll
  for (int s = 0; s < 2; s++) {
    int seg = w * 2 + s;
    int r = seg * 8 + (lane >> 3);
    int k8 = lane & 7;
    krow[s] = r; kkb[s] = k8 ^ (r & 7); klds[s] = seg * 512;
  }
  auto STAGEK = [&](int bb, int ci) {
#pragma unroll
    for (int s = 0; s < 2; s++) {
      size_t ga = ((size_t)(bh * TT + ci * 128 + krow[s])) * DD + kkb[s] * 8;
      glds16(&Kh[ga], &Khs[bb][klds[s]]);
      glds16(&Kl[ga], &Kls[bb][klds[s]]);
    }
  };

  for (int half = 0; half < 2; half++) {
    const int rt = half ? (15 - pairid) : pairid;
    const int row0 = rt * 128;
    const int nch = rt + 1;
    __syncthreads();    // previous half fully done (no outstanding vmcnt here)
    // stage Q tile (plain stores, swizzled chunk layout)
#pragma unroll
    for (int cc = 0; cc < 2; cc++) {
      int c = cc * 512 + tid;
      int r = c >> 3, k8 = c & 7;
      int so = r * 64 + ((k8 ^ (r & 7)) * 8);
      size_t ga = ((size_t)(bh * TT + row0 + r)) * DD + k8 * 8;
      *reinterpret_cast<bf16x8*>(&Qhs[so]) = *reinterpret_cast<const bf16x8*>(&Qh[ga]);
      *reinterpret_cast<bf16x8*>(&Qls[so]) = *reinterpret_cast<const bf16x8*>(&Ql[ga]);
    }
    __syncthreads();
    // hoist Q fragments (chunk-invariant)
    bf16x8 aq[2][2], aql[2][2];
#pragma unroll
    for (int ks = 0; ks < 2; ks++)
#pragma unroll
      for (int i = 0; i < 2; i++) {
        int ar = wm * 32 + i * 16 + l15;
        int off = ar * 64 + (((ks * 4 + l4) ^ (ar & 7)) * 8);
        aq[ks][i]  = *reinterpret_cast<const bf16x8*>(&Qhs[off]);
        aql[ks][i] = *reinterpret_cast<const bf16x8*>(&Qls[off]);
      }

    float rsum[2][4];
#pragma unroll
    for (int i = 0; i < 2; i++)
#pragma unroll
      for (int r = 0; r < 4; r++) rsum[i][r] = 0.f;
    float invl[2][4];

    for (int sweep = 0; sweep < 2; sweep++) {
      STAGEK(0, 0);
      if (nch > 1) STAGEK(1, 1);
      int cur = 0;
      for (int ci = 0; ci < nch; ci++) {
        if (ci + 1 < nch) WAIT_VM(4); else WAIT_VM(0);
        BAR();
        f32x4 acc[2][4] = {};
#pragma unroll
        for (int ks = 0; ks < 2; ks++) {
#pragma unroll
          for (int j = 0; j < 4; j++) {
            int br = wn * 64 + j * 16 + l15;
            int off = br * 64 + (((ks * 4 + l4) ^ (br & 7)) * 8);
            bf16x8 bh_ = *reinterpret_cast<const bf16x8*>(&Khs[cur][off]);
            bf16x8 bl_ = *reinterpret_cast<const bf16x8*>(&Kls[cur][off]);
#pragma unroll
            for (int i = 0; i < 2; i++) {
              acc[i][j] = __builtin_amdgcn_mfma_f32_16x16x32_bf16(aq[ks][i], bh_, acc[i][j], 0, 0, 0);
              acc[i][j] = __builtin_amdgcn_mfma_f32_16x16x32_bf16(aq[ks][i], bl_, acc[i][j], 0, 0, 0);
              acc[i][j] = __builtin_amdgcn_mfma_f32_16x16x32_bf16(aql[ks][i], bh_, acc[i][j], 0, 0, 0);
            }
          }
        }
        const bool diag = (ci == rt);
        if (sweep == 0) {
#pragma unroll
          for (int i = 0; i < 2; i++)
#pragma unroll
            for (int r = 0; r < 4; r++) {
              int row = row0 + wm * 32 + i * 16 + l4 * 4 + r;
              float s = 0.f;
#pragma unroll
              for (int j = 0; j < 4; j++) {
                int key = ci * 128 + wn * 64 + j * 16 + l15;
                float p = __expf(acc[i][j][r] * QSCALE);
                if (diag && key > row) p = 0.f;
                s += p;
              }
              rsum[i][r] += s;
            }
          WAIT_LGKM0;
          BAR();   // all waves done reading Khs[cur]
          if (ci + 2 < nch) STAGEK(cur, ci + 2);
        } else {
          float cp[4];
#pragma unroll
          for (int j = 0; j < 4; j++) cp[j] = 0.f;
#pragma unroll
          for (int i = 0; i < 2; i++)
#pragma unroll
            for (int r = 0; r < 4; r++) {
              int row = row0 + wm * 32 + i * 16 + l4 * 4 + r;
              float il = invl[i][r];
#pragma unroll
              for (int j = 0; j < 4; j++) {
                int key = ci * 128 + wn * 64 + j * 16 + l15;
                float p = __expf(acc[i][j][r] * QSCALE) * il;
                if (diag && key > row) p = 0.f;
                cp[j] += p;
              }
            }
#pragma unroll
          for (int j = 0; j < 4; j++) {
            float v = cp[j];
            v += __shfl_xor(v, 16); v += __shfl_xor(v, 32);
            cp[j] = v;
          }
          WAIT_LGKM0;
          BAR();   // Khs[cur] reads done; prev chunk's csw reads done
          if (ci + 2 < nch) STAGEK(cur, ci + 2);
          if (l4 == 0) {
#pragma unroll
            for (int j = 0; j < 4; j++)
              csw[w * 128 + wn * 64 + j * 16 + l15] = cp[j];
          }
          WAIT_LGKM0;
          BAR();   // csw visible (DS-only fence; prefetch stays in flight)
          if (tid < 128) {
            int wnc = tid >> 6;
            float s = csw[(0 * 2 + wnc) * 128 + tid] + csw[(1 * 2 + wnc) * 128 + tid] +
                      csw[(2 * 2 + wnc) * 128 + tid] + csw[(3 * 2 + wnc) * 128 + tid];
            size_t pi = ((size_t)(bh * 8 + pairid)) * 2048 + ci * 128 + tid;
            bool wr = (half == 0) || (ci > pairid);
            part[pi] = wr ? s : (part[pi] + s);
          }
        }
        cur ^= 1;
      }
      if (sweep == 0) {
#pragma unroll
        for (int i = 0; i < 2; i++)
#pragma unroll
          for (int r = 0; r < 4; r++) {
            float v = rsum[i][r];
            v += __shfl_xor(v, 1); v += __shfl_xor(v, 2);
            v += __shfl_xor(v, 4); v += __shfl_xor(v, 8);
            rsum[i][r] = v;
          }
        __syncthreads();   // outstanding vmcnt == 0 here (final iter drained)
        if (l15 == 0) {
#pragma unroll
          for (int i = 0; i < 2; i++)
#pragma unroll
            for (int r = 0; r < 4; r++)
              rsb[wn * 128 + wm * 32 + i * 16 + l4 * 4 + r] = rsum[i][r];
        }
        __syncthreads();
#pragma unroll
        for (int i = 0; i < 2; i++)
#pragma unroll
          for (int r = 0; r < 4; r++) {
            int rl = wm * 32 + i * 16 + l4 * 4 + r;
            invl[i][r] = 1.0f / (rsb[rl] + rsb[128 + rl]);
          }
      }
    }
  }
}

// ---------------- Top-K select + gather (K f16, V f16-transposed) ----------------
__global__ __launch_bounds__(256) void topk_gather_kernel(
    const float* __restrict__ part,
    const unsigned short* __restrict__ Kh, const unsigned short* __restrict__ Kl,
    const float* __restrict__ V,
    unsigned short* __restrict__ Kf, unsigned short* __restrict__ Vt)
{
  const int bh = blockIdx.x, tid = threadIdx.x;
  const int lane = tid & 63, w = tid >> 6;
  __shared__ int redi[4];
  __shared__ int stot;
  __shared__ int base[256];
  __shared__ int idxb[KKEEP];
  unsigned u[8];
#pragma unroll
  for (int k = 0; k < 8; k++) {
    int e = tid * 8 + k;
    float s = 0.f;
#pragma unroll
    for (int p = 0; p < 8; p++)
      if (e < (16 - p) * 128) s += part[((size_t)(bh * 8 + p)) * 2048 + e];
    float v = (e >= TT - REC) ? 3.0e3f : s;
    u[k] = __float_as_uint(v);
  }
  unsigned lo = 0u, hi = 0x7f800000u;
  for (int it = 0; it < 31; it++) {
    unsigned mid = lo + ((hi - lo + 1) >> 1);
    int c = 0;
#pragma unroll
    for (int k = 0; k < 8; k++) c += (u[k] >= mid) ? 1 : 0;
#pragma unroll
    for (int off = 1; off <= 32; off <<= 1) c += __shfl_xor(c, off);
    if (lane == 0) redi[w] = c;
    __syncthreads();
    int tot = redi[0] + redi[1] + redi[2] + redi[3];
    if (tot >= KKEEP) lo = mid; else hi = mid - 1;
    __syncthreads();
  }
  const unsigned vstar = lo;
  int cgt = 0, ceq = 0;
#pragma unroll
  for (int k = 0; k < 8; k++) { cgt += (u[k] > vstar) ? 1 : 0; ceq += (u[k] == vstar) ? 1 : 0; }
  base[tid] = cgt; __syncthreads();
  if (tid == 0) {
    int run = 0;
    for (int i = 0; i < 256; i++) { int t = base[i]; base[i] = run; run += t; }
    stot = run;
  }
  __syncthreads();
  int off1 = base[tid];
#pragma unroll
  for (int k = 0; k < 8; k++)
    if (u[k] > vstar) idxb[off1++] = tid * 8 + k;
  __syncthreads();
  base[tid] = ceq; __syncthreads();
  if (tid == 0) {
    int run = 0;
    for (int i = 0; i < 256; i++) { int t = base[i]; base[i] = run; run += t; }
  }
  __syncthreads();
  int off2 = stot + base[tid];
#pragma unroll
  for (int k = 0; k < 8; k++)
    if (u[k] == vstar) { if (off2 < KKEEP) idxb[off2] = tid * 8 + k; off2++; }
  __syncthreads();
  // K -> f16 plane [bh][KPAD][64], zero-padded
  for (int f = tid; f < KPAD * 8; f += 256) {
    int kk = f >> 3, c8 = f & 7;
    union { _Float16 h[8]; uint4 v; } o;
#pragma unroll
    for (int j = 0; j < 8; j++) o.h[j] = (_Float16)0.f;
    if (kk < KKEEP) {
      int sr = idxb[kk];
      bf16x8 hv = *reinterpret_cast<const bf16x8*>(&Kh[((size_t)(bh * TT + sr)) * DD + c8 * 8]);
      bf16x8 lv = *reinterpret_cast<const bf16x8*>(&Kl[((size_t)(bh * TT + sr)) * DD + c8 * 8]);
#pragma unroll
      for (int j = 0; j < 8; j++)
        o.h[j] = (_Float16)(bf_up((unsigned short)hv[j]) + bf_up((unsigned short)lv[j]));
    }
    *reinterpret_cast<uint4*>(&Kf[((size_t)(bh * KPAD) + kk) * DD + c8 * 8]) = o.v;
  }
  // V -> f16 transposed plane [bh][64][KPAD], zero-padded
  for (int f = tid; f < KPAD * 8; f += 256) {
    int kk = f >> 3, d8 = f & 7;
    float vv[8];
#pragma unroll
    for (int j = 0; j < 8; j++) vv[j] = 0.f;
    if (kk < KKEEP) {
      int sr = idxb[kk];
      float4 a = *reinterpret_cast<const float4*>(&V[((size_t)(bh * TT + sr)) * DD + d8 * 8]);
      float4 b = *reinterpret_cast<const float4*>(&V[((size_t)(bh * TT + sr)) * DD + d8 * 8 + 4]);
      vv[0] = a.x; vv[1] = a.y; vv[2] = a.z; vv[3] = a.w;
      vv[4] = b.x; vv[5] = b.y; vv[6] = b.z; vv[7] = b.w;
    }
#pragma unroll
    for (int j = 0; j < 8; j++) {
      union { _Float16 h; unsigned short s; } t;
      t.h = (_Float16)vv[j];
      Vt[((size_t)(bh * DD) + d8 * 8 + j) * KPAD + kk] = t.s;
    }
  }
}

// ---------------- Pass-2 attention: f16 MFMA, counted pipeline ----------------
__global__ __launch_bounds__(256) void attn4_kernel(
    const unsigned short* __restrict__ Qh, const unsigned short* __restrict__ Ql,
    const unsigned short* __restrict__ Kf, const unsigned short* __restrict__ Vt,
    unsigned short* __restrict__ AOh, unsigned short* __restrict__ AOl)
{
  const int rt = blockIdx.y, bh = blockIdx.x;
  const int tid = threadIdx.x;
  const int w = tid >> 6, lane = tid & 63;
  const int l15 = lane & 15, l4 = lane >> 4;
  __shared__ __align__(16) unsigned short Qs[64 * 64];
  __shared__ __align__(16) unsigned short Ks[2][64 * 64];
  __shared__ __align__(16) unsigned short Vs[2][64 * 64];
  __shared__ float LDSo[4][64][16];
  const int row0 = rt * 64;

  int srow[2], skb[2], slds[2];
#pragma unroll
  for (int s = 0; s < 2; s++) {
    int seg = w * 2 + s;
    int r = seg * 8 + (lane >> 3);
    int k8 = lane & 7;
    srow[s] = r; skb[s] = k8 ^ (r & 7); slds[s] = seg * 512;
  }
  auto STAGEA = [&](int bb, int ci) {
#pragma unroll
    for (int s = 0; s < 2; s++) {
      glds16(&Kf[((size_t)(bh * KPAD) + ci * 64 + srow[s]) * DD + skb[s] * 8], &Ks[bb][slds[s]]);
      glds16(&Vt[((size_t)(bh * DD) + srow[s]) * KPAD + ci * 64 + skb[s] * 8], &Vs[bb][slds[s]]);
    }
  };

  // stage Q (f16) from split-bf16 planes (plain ds stores)
#pragma unroll
  for (int it = 0; it < 2; it++) {
    int idx = it * 256 + tid;
    int r = idx >> 3, k8 = idx & 7;
    size_t ga = ((size_t)(bh * TT + row0 + r)) * DD + k8 * 8;
    bf16x8 hv = *reinterpret_cast<const bf16x8*>(&Qh[ga]);
    bf16x8 lv = *reinterpret_cast<const bf16x8*>(&Ql[ga]);
    union { _Float16 h[8]; uint4 v; } q16;
#pragma unroll
    for (int j = 0; j < 8; j++)
      q16.h[j] = (_Float16)(bf_up((unsigned short)hv[j]) + bf_up((unsigned short)lv[j]));
    *reinterpret_cast<uint4*>(&Qs[r * 64 + ((k8 ^ (r & 7)) * 8)]) = q16.v;
  }
  STAGEA(0, 0);
  STAGEA(1, 1);
  WAIT_LGKM0;    // Q ds-writes visible (prefetch stays in flight)
  BAR();
  // hoist Q B-fragments (wave's 16 q rows)
  f16x8 bq[2];
#pragma unroll
  for (int ks = 0; ks < 2; ks++) {
    int br = w * 16 + l15;
    bq[ks] = *reinterpret_cast<const f16x8*>(&Qs[br * 64 + (((ks * 4 + l4) ^ (br & 7)) * 8)]);
  }

  f32x4 acc_o[4] = {};
  float rsum = 0.f;
  int cur = 0;

  for (int ci = 0; ci < 7; ci++) {
    if (ci + 1 < 7) WAIT_VM(4); else WAIT_VM(0);
    BAR();
    // QK^T swapped: C[key][q]
    f32x4 accs[4] = {};
#pragma unroll
    for (int ks = 0; ks < 2; ks++) {
#pragma unroll
      for (int i = 0; i < 4; i++) {
        int kr = i * 16 + l15;
        f16x8 af = *reinterpret_cast<const f16x8*>(&Ks[cur][kr * 64 + (((ks * 4 + l4) ^ (kr & 7)) * 8)]);
        accs[i] = __builtin_amdgcn_mfma_f32_16x16x32_f16(af, bq[ks], accs[i], 0, 0, 0);
      }
    }
    float p[4][4];
#pragma unroll
    for (int i = 0; i < 4; i++)
#pragma unroll
      for (int r = 0; r < 4; r++) {
        int gk = ci * 64 + i * 16 + l4 * 4 + r;
        float pp = __expf(accs[i][r] * QSCALE);
        if (gk >= KKEEP) pp = 0.f;
        p[i][r] = pp;
        rsum += pp;
      }
    unsigned pkU[4][2];
#pragma unroll
    for (int i = 0; i < 4; i++) {
      pkU[i][0] = pkf16(p[i][0], p[i][1]);
      pkU[i][1] = pkf16(p[i][2], p[i][3]);
    }
#pragma unroll
    for (int ks = 0; ks < 2; ks++) {
      union { f16x8 h; unsigned u[4]; } bp;
#pragma unroll
      for (int wp = 0; wp < 4; wp++) {
        int src = ((l4 & 1) * 2 + (wp >> 1)) * 16 + l15;
        unsigned v0 = (unsigned)__shfl((int)pkU[ks * 2][wp & 1], src);
        unsigned v1 = (unsigned)__shfl((int)pkU[ks * 2 + 1][wp & 1], src);
        bp.u[wp] = (l4 & 2) ? v1 : v0;
      }
#pragma unroll
      for (int i = 0; i < 4; i++) {
        int dr = i * 16 + l15;
        f16x8 av = *reinterpret_cast<const f16x8*>(&Vs[cur][dr * 64 + (((ks * 4 + l4) ^ (dr & 7)) * 8)]);
        acc_o[i] = __builtin_amdgcn_mfma_f32_16x16x32_f16(av, bp.h, acc_o[i], 0, 0, 0);
      }
    }
    WAIT_LGKM0;
    BAR();
    if (ci + 2 < 7) STAGEA(cur, ci + 2);
    cur ^= 1;
  }
  // normalize and transpose via LDS (outstanding vmcnt == 0 here)
  rsum += __shfl_xor(rsum, 16);
  rsum += __shfl_xor(rsum, 32);
  float inv = 1.0f / rsum;
#pragma unroll
  for (int i = 0; i < 4; i++)
#pragma unroll
    for (int r = 0; r < 4; r++)
      LDSo[w][i * 16 + l4 * 4 + r][l15] = acc_o[i][r] * inv;
  __syncthreads();
  const int b = bh >> 4, h = bh & 15;
#pragma unroll
  for (int uu = 0; uu < 2; uu++) {
    int u = uu * 64 + lane;
    int q = u >> 3, dc = u & 7;
    int row = row0 + w * 16 + q;
    union { unsigned short s[8]; uint4 v; } sh, sl;
#pragma unroll
    for (int j = 0; j < 8; j++) {
      float v = LDSo[w][dc * 8 + j][q];
      unsigned short hh = bf_rn(v);
      sh.s[j] = hh;
      sl.s[j] = bf_rn(v - bf_up(hh));
    }
    size_t addr = ((size_t)(b * TT + row)) * EE + h * DD + dc * 8;
    *reinterpret_cast<uint4*>(&AOh[addr]) = sh.v;
    *reinterpret_cast<uint4*>(&AOl[addr]) = sl.v;
  }
}

extern "C" void kernel_launch(void* const* d_in, const int* in_sizes, int n_in,
                              void* d_out, int out_size, void* d_ws, size_t ws_size,
                              hipStream_t stream)
{
  const float* x     = (const float*)d_in[0];
  const float* Wattn = (const float*)d_in[1];
  const float* Wproj = (const float*)d_in[2];
  float* out = (float*)d_out;
  float* ws  = (float*)d_ws;

  const size_t SZQ = (size_t)NBH * TT * DD;            // 4,194,304 elements
  const size_t SZK = (size_t)NBH * KPAD * DD;          // 917,504
  float* Vb   = ws;                                    // f32 V
  float* part = Vb + SZQ;                              // 524,288 f
  unsigned short* Kf  = (unsigned short*)(part + (size_t)NBH * 8 * TT);
  unsigned short* Vt  = Kf + SZK;
  unsigned short* Qhp = Vt + SZK;
  unsigned short* Qlp = Qhp + SZQ;
  unsigned short* Khp = Qlp + SZQ;
  unsigned short* Klp = Khp + SZQ;
  unsigned short* xh  = Klp + SZQ;                     // x splits (dead after QKV)
  unsigned short* xl  = xh + (size_t)4096 * 1024;
  unsigned short* Wh  = xl + (size_t)4096 * 1024;      // W_attn splits
  unsigned short* Wl  = Wh + (size_t)3072 * 1024;
  unsigned short* AOh = xh;                            // alias
  unsigned short* AOl = xl;
  unsigned short* Ph  = Wh;                            // alias (after QKV GEMMs)
  unsigned short* Pl  = Ph + (size_t)1024 * 1024;

  const size_t needB =
      ((size_t)SZQ + (size_t)NBH * 8 * TT) * 4 +
      ((size_t)2 * SZK + (size_t)4 * SZQ + (size_t)2 * 4096 * 1024 + (size_t)2 * 3072 * 1024) * 2;
  if (ws_size < needB) return;   // ~85.5 MB

  // 0) split x + W_attn into bf16 hi/lo planes (merged launch)
  split2_kernel<<<1024, 256, 0, stream>>>(x, Wattn, xh, xl, Wh, Wl);
  // 1) QKV projection: Q/K columns (3-product) and V columns (1-product)
  gemm_pipe<false, 1><<<dim3(16, 32), 256, 0, stream>>>(xh, xl, Wh, Wl, nullptr,
      Qhp, Qlp, Khp, Klp, nullptr, 4096, 3072, 1024, 0);
  gemm_pipe<true, 1><<<dim3(8, 32), 256, 0, stream>>>(xh, xl, Wh, Wl, nullptr,
      nullptr, nullptr, nullptr, nullptr, Vb, 4096, 3072, 1024, 2048);
  // 1b) split W_proj (aliases W_attn splits; stream-ordered after QKV GEMMs)
  split_kernel<<<256, 256, 0, stream>>>(Wproj, Ph, Pl, 1024 * 1024);
  // 2) causal softmax column sums (counted pipeline)
  importance4_kernel<<<dim3(NBH, 8), 512, 0, stream>>>(Qhp, Qlp, Khp, Klp, part);
  // 3) exact top-391 + gather
  topk_gather_kernel<<<NBH, 256, 0, stream>>>(part, Khp, Klp, Vb, Kf, Vt);
  // 4) pruned-key attention (counted pipeline)
  attn4_kernel<<<dim3(NBH, 32), 256, 0, stream>>>(Qhp, Qlp, Kf, Vt, AOh, AOl);
  // 5) output projection
  gemm_pipe<false, 0><<<dim3(8, 32), 256, 0, stream>>>(AOh, AOl, Ph, Pl, out,
      nullptr, nullptr, nullptr, nullptr, nullptr, 4096, 1024, 1024, 0);
}

// Round 8
// 261.888 us; speedup vs baseline: 1.1964x; 1.0120x over previous
//
#include <hip/hip_runtime.h>
#include <hip/hip_bf16.h>

// PrunedKVAttention: B=2,T=2048,E=1024,H=16,D=64,K_KEEP=391,RECENCY=64
// Round 8: importance restructure -- 512 blocks (2/CU), Q frags direct from
// global (LDS 69KB), sweep-1 single-product. Private part slabs (16/bh).
// Everything else identical to round 7. absmax canary 4.8828e-4.

#define TT 2048
#define EE 1024
#define HH 16
#define DD 64
#define KKEEP 391
#define REC 64
#define NBH 32
#define QSCALE 0.125f
#define KPAD 448

typedef short bf16x8 __attribute__((ext_vector_type(8)));
typedef _Float16 f16x8 __attribute__((ext_vector_type(8)));
typedef float f32x4 __attribute__((ext_vector_type(4)));

#define WAIT_VM(N) asm volatile("s_waitcnt vmcnt(" #N ")" ::: "memory")
#define WAIT_LGKM0 asm volatile("s_waitcnt lgkmcnt(0)" ::: "memory")
#define BAR() __builtin_amdgcn_s_barrier()

static __device__ inline unsigned short bf_rn(float x) {
  unsigned u = __float_as_uint(x);
  unsigned r = u + 0x7fffu + ((u >> 16) & 1u);
  return (unsigned short)(r >> 16);
}
static __device__ inline float bf_up(unsigned short h) {
  return __uint_as_float((unsigned)h << 16);
}
static __device__ inline unsigned pkf16(float a, float b) {
  union { _Float16 h[2]; unsigned u; } t;
  t.h[0] = (_Float16)a; t.h[1] = (_Float16)b; return t.u;
}
// async global->LDS, 16B per lane; LDS dest = wave-uniform base + lane*16
static __device__ inline void glds16(const void* g, void* l) {
  __builtin_amdgcn_global_load_lds(
      (const __attribute__((address_space(1))) void*)g,
      (__attribute__((address_space(3))) void*)l, 16, 0, 0);
}

// ---------------- split f32 -> (hi, lo) bf16 planes ----------------
static __device__ inline void split4(const float* __restrict__ src,
                                     unsigned short* __restrict__ ho,
                                     unsigned short* __restrict__ lo_, int i)
{
  float4 v = *reinterpret_cast<const float4*>(&src[i]);
  ushort4 hh, ll;
  float f;
  hh.x = bf_rn(v.x); f = bf_up(hh.x); ll.x = bf_rn(v.x - f);
  hh.y = bf_rn(v.y); f = bf_up(hh.y); ll.y = bf_rn(v.y - f);
  hh.z = bf_rn(v.z); f = bf_up(hh.z); ll.z = bf_rn(v.z - f);
  hh.w = bf_rn(v.w); f = bf_up(hh.w); ll.w = bf_rn(v.w - f);
  *reinterpret_cast<ushort4*>(&ho[i]) = hh;
  *reinterpret_cast<ushort4*>(&lo_[i]) = ll;
}

__global__ __launch_bounds__(256) void split_kernel(
    const float* __restrict__ src, unsigned short* __restrict__ ho,
    unsigned short* __restrict__ lo_, int n)
{
  int i = (blockIdx.x * 256 + threadIdx.x) * 4;
  const int stride = gridDim.x * 1024;
  for (; i < n; i += stride) split4(src, ho, lo_, i);
}

// merged x + W_attn split
__global__ __launch_bounds__(256) void split2_kernel(
    const float* __restrict__ x, const float* __restrict__ wa,
    unsigned short* __restrict__ xh, unsigned short* __restrict__ xl,
    unsigned short* __restrict__ wh, unsigned short* __restrict__ wl)
{
  const int n1 = 4096 * 1024, n2 = 3072 * 1024;
  int i = (blockIdx.x * 256 + threadIdx.x) * 4;
  const int stride = gridDim.x * 1024;
  for (; i < n1 + n2; i += stride) {
    if (i < n1) split4(x, xh, xl, i);
    else        split4(wa, wh, wl, i - n1);
  }
}

// ---------------- MFMA GEMM (NT), counted-vmcnt 2-deep pipeline ----------------
// VB: single-product V-column blocks. MODE 0: plain C. MODE 1: QKV scatter.
template<bool VB, int MODE>
__global__ __launch_bounds__(256) void gemm_pipe(
    const unsigned short* __restrict__ Ah, const unsigned short* __restrict__ Al,
    const unsigned short* __restrict__ Bh, const unsigned short* __restrict__ Bl,
    float* __restrict__ Cc, unsigned short* __restrict__ Qho, unsigned short* __restrict__ Qlo,
    unsigned short* __restrict__ Kho, unsigned short* __restrict__ Klo,
    float* __restrict__ Vo, int M, int N, int Kd, int nOff)
{
  __shared__ __align__(16) unsigned short Ahs[2][128 * 32];
  __shared__ __align__(16) unsigned short Bhs[2][128 * 32];
  __shared__ __align__(16) unsigned short Als[VB ? 1 : 2][128 * 32];
  __shared__ __align__(16) unsigned short Bls[VB ? 1 : 2][128 * 32];
  const int tid = threadIdx.x;
  const int m0 = blockIdx.y * 128, n0 = nOff + blockIdx.x * 128;
  const int w = tid >> 6, lane = tid & 63;
  const int wm = w >> 1, wn = w & 1;
  const int l15 = lane & 15, l4 = lane >> 4;

  size_t gA[2], gB[2]; int ldso[2];
#pragma unroll
  for (int s = 0; s < 2; s++) {
    int seg = w * 2 + s;
    int r = seg * 16 + (lane >> 2);
    int kb = (lane & 3) ^ ((r >> 1) & 3);
    gA[s] = (size_t)(m0 + r) * Kd + kb * 8;
    gB[s] = (size_t)(n0 + r) * Kd + kb * 8;
    ldso[s] = seg * 512;
  }
  auto STAGE = [&](int bb, int k0) {
#pragma unroll
    for (int s = 0; s < 2; s++) {
      glds16(&Ah[gA[s] + k0], &Ahs[bb][ldso[s]]);
      glds16(&Bh[gB[s] + k0], &Bhs[bb][ldso[s]]);
      if (!VB) {
        glds16(&Al[gA[s] + k0], &Als[bb][ldso[s]]);
        glds16(&Bl[gB[s] + k0], &Bls[bb][ldso[s]]);
      }
    }
  };

  f32x4 acc[4][4] = {};

  STAGE(0, 0);
  STAGE(1, 32);
  int cur = 0;
  for (int k0 = 0; k0 < Kd; k0 += 32) {
    if (k0 + 32 < Kd) { if (VB) WAIT_VM(4); else WAIT_VM(8); }
    else WAIT_VM(0);
    BAR();
    bf16x8 ah[4], al[4], bh[4], bl[4];
#pragma unroll
    for (int i = 0; i < 4; i++) {
      int ar = wm * 64 + i * 16 + l15;
      int aoff = ar * 32 + ((l4 ^ ((ar >> 1) & 3)) * 8);
      ah[i] = *reinterpret_cast<const bf16x8*>(&Ahs[cur][aoff]);
      int br = wn * 64 + i * 16 + l15;
      int boff = br * 32 + ((l4 ^ ((br >> 1) & 3)) * 8);
      bh[i] = *reinterpret_cast<const bf16x8*>(&Bhs[cur][boff]);
      if (!VB) {
        al[i] = *reinterpret_cast<const bf16x8*>(&Als[cur][aoff]);
        bl[i] = *reinterpret_cast<const bf16x8*>(&Bls[cur][boff]);
      }
    }
#pragma unroll
    for (int i = 0; i < 4; i++)
#pragma unroll
      for (int j = 0; j < 4; j++) {
        acc[i][j] = __builtin_amdgcn_mfma_f32_16x16x32_bf16(ah[i], bh[j], acc[i][j], 0, 0, 0);
        if (!VB) {
          acc[i][j] = __builtin_amdgcn_mfma_f32_16x16x32_bf16(ah[i], bl[j], acc[i][j], 0, 0, 0);
          acc[i][j] = __builtin_amdgcn_mfma_f32_16x16x32_bf16(al[i], bh[j], acc[i][j], 0, 0, 0);
        }
      }
    WAIT_LGKM0;
    BAR();
    if (k0 + 64 < Kd) STAGE(cur, k0 + 64);
    cur ^= 1;
  }

  if (MODE == 0) {
#pragma unroll
    for (int i = 0; i < 4; i++) {
      int mrow0 = m0 + wm * 64 + i * 16 + l4 * 4;
#pragma unroll
      for (int j = 0; j < 4; j++) {
        int ncol = n0 + wn * 64 + j * 16 + l15;
#pragma unroll
        for (int r = 0; r < 4; r++)
          Cc[(size_t)(mrow0 + r) * N + ncol] = acc[i][j][r];
      }
    }
  } else if (VB) {
#pragma unroll
    for (int j = 0; j < 4; j++) {
      int n = n0 + wn * 64 + j * 16 + l15;
      int rr = n & 1023;
      int h = rr >> 6, d0 = rr & 63;
#pragma unroll
      for (int i = 0; i < 4; i++) {
        int mrow0 = m0 + wm * 64 + i * 16 + l4 * 4;
#pragma unroll
        for (int r = 0; r < 4; r++) {
          int m = mrow0 + r;
          int b = m >> 11, t = m & 2047;
          Vo[((size_t)((b * HH + h) * TT + t)) * DD + d0] = acc[i][j][r];
        }
      }
    }
  } else {
#pragma unroll
    for (int j = 0; j < 4; j++) {
      int n = n0 + wn * 64 + j * 16 + l15;
      int p = n >> 10, rr = n & 1023;
      int h = rr >> 6, d0 = rr & 63;
#pragma unroll
      for (int i = 0; i < 4; i++) {
        int mrow0 = m0 + wm * 64 + i * 16 + l4 * 4;
#pragma unroll
        for (int r = 0; r < 4; r++) {
          int m = mrow0 + r;
          int b = m >> 11, t = m & 2047;
          size_t idx = ((size_t)((b * HH + h) * TT + t)) * DD + d0;
          float v = acc[i][j][r];
          unsigned short hi_ = bf_rn(v);
          unsigned short lo2 = bf_rn(v - bf_up(hi_));
          if (p == 0) { Qho[idx] = hi_; Qlo[idx] = lo2; }
          else        { Kho[idx] = hi_; Klo[idx] = lo2; }
        }
      }
    }
  }
}

// ---------------- Importance: one row-tile per block, 16 private slabs/bh ----
// grid (bh=32, y=8, z=2): rt = z ? 15-y : y. 512 thr = 8 waves (4x2).
// Sweep 1 (rowsums): single product, Kh only, vmcnt(2). Sweep 2: 3 products.
__global__ __launch_bounds__(512) void importance5_kernel(
    const unsigned short* __restrict__ Qh, const unsigned short* __restrict__ Ql,
    const unsigned short* __restrict__ Kh, const unsigned short* __restrict__ Kl,
    float* __restrict__ part)
{
  const int bh = blockIdx.x;
  const int rt = blockIdx.z ? (15 - (int)blockIdx.y) : (int)blockIdx.y;
  const int slab = ((int)blockIdx.y << 1) | (int)blockIdx.z;
  const int row0 = rt * 128;
  const int nch = rt + 1;
  const int tid = threadIdx.x;
  const int w = tid >> 6, lane = tid & 63;
  const int wm = w >> 1, wn = w & 1;
  const int l15 = lane & 15, l4 = lane >> 4;
  __shared__ __align__(16) unsigned short Khs[2][128 * 64];   // 32 KB
  __shared__ __align__(16) unsigned short Kls[2][128 * 64];   // 32 KB
  __shared__ float csw[8 * 128];                              // 4 KB
  __shared__ float rsb[2 * 128];                              // 1 KB

  int krow[2], kkb[2], klds[2];
#pragma unroll
  for (int s = 0; s < 2; s++) {
    int seg = w * 2 + s;
    int r = seg * 8 + (lane >> 3);
    int k8 = lane & 7;
    krow[s] = r; kkb[s] = k8 ^ (r & 7); klds[s] = seg * 512;
  }
  auto STAGEK1 = [&](int bb, int ci) {
#pragma unroll
    for (int s = 0; s < 2; s++) {
      size_t ga = ((size_t)(bh * TT + ci * 128 + krow[s])) * DD + kkb[s] * 8;
      glds16(&Kh[ga], &Khs[bb][klds[s]]);
    }
  };
  auto STAGEK2 = [&](int bb, int ci) {
#pragma unroll
    for (int s = 0; s < 2; s++) {
      size_t ga = ((size_t)(bh * TT + ci * 128 + krow[s])) * DD + kkb[s] * 8;
      glds16(&Kh[ga], &Khs[bb][klds[s]]);
      glds16(&Kl[ga], &Kls[bb][klds[s]]);
    }
  };

  // Q fragments direct from global (chunk-invariant; wave covers 2KB block)
  bf16x8 aq[2][2], aql[2][2];
#pragma unroll
  for (int ks = 0; ks < 2; ks++)
#pragma unroll
    for (int i = 0; i < 2; i++) {
      int ar = wm * 32 + i * 16 + l15;
      size_t ga = ((size_t)(bh * TT + row0 + ar)) * DD + (ks * 4 + l4) * 8;
      aq[ks][i]  = *reinterpret_cast<const bf16x8*>(&Qh[ga]);
      aql[ks][i] = *reinterpret_cast<const bf16x8*>(&Ql[ga]);
    }

  float rsum[2][4];
#pragma unroll
  for (int i = 0; i < 2; i++)
#pragma unroll
    for (int r = 0; r < 4; r++) rsum[i][r] = 0.f;
  float invl[2][4];

  // ================= sweep 1: row sums (single product) =================
  STAGEK1(0, 0);
  if (nch > 1) STAGEK1(1, 1);
  int cur = 0;
  for (int ci = 0; ci < nch; ci++) {
    if (ci + 1 < nch) WAIT_VM(2); else WAIT_VM(0);
    BAR();
    f32x4 acc[2][4] = {};
#pragma unroll
    for (int ks = 0; ks < 2; ks++) {
#pragma unroll
      for (int j = 0; j < 4; j++) {
        int br = wn * 64 + j * 16 + l15;
        int off = br * 64 + (((ks * 4 + l4) ^ (br & 7)) * 8);
        bf16x8 bh_ = *reinterpret_cast<const bf16x8*>(&Khs[cur][off]);
#pragma unroll
        for (int i = 0; i < 2; i++)
          acc[i][j] = __builtin_amdgcn_mfma_f32_16x16x32_bf16(aq[ks][i], bh_, acc[i][j], 0, 0, 0);
      }
    }
    const bool diag = (ci == rt);
#pragma unroll
    for (int i = 0; i < 2; i++)
#pragma unroll
      for (int r = 0; r < 4; r++) {
        int row = row0 + wm * 32 + i * 16 + l4 * 4 + r;
        float s = 0.f;
#pragma unroll
        for (int j = 0; j < 4; j++) {
          int key = ci * 128 + wn * 64 + j * 16 + l15;
          float p = __expf(acc[i][j][r] * QSCALE);
          if (diag && key > row) p = 0.f;
          s += p;
        }
        rsum[i][r] += s;
      }
    WAIT_LGKM0;
    BAR();
    if (ci + 2 < nch) STAGEK1(cur, ci + 2);
    cur ^= 1;
  }
  // reduce rowsums: over 16 cols (l15), then across wn pair via LDS
#pragma unroll
  for (int i = 0; i < 2; i++)
#pragma unroll
    for (int r = 0; r < 4; r++) {
      float v = rsum[i][r];
      v += __shfl_xor(v, 1); v += __shfl_xor(v, 2);
      v += __shfl_xor(v, 4); v += __shfl_xor(v, 8);
      rsum[i][r] = v;
    }
  __syncthreads();   // vmcnt drained (last iter waited 0)
  if (l15 == 0) {
#pragma unroll
    for (int i = 0; i < 2; i++)
#pragma unroll
      for (int r = 0; r < 4; r++)
        rsb[wn * 128 + wm * 32 + i * 16 + l4 * 4 + r] = rsum[i][r];
  }
  __syncthreads();
#pragma unroll
  for (int i = 0; i < 2; i++)
#pragma unroll
    for (int r = 0; r < 4; r++) {
      int rl = wm * 32 + i * 16 + l4 * 4 + r;
      invl[i][r] = 1.0f / (rsb[rl] + rsb[128 + rl]);
    }

  // ================= sweep 2: column sums (3 products) =================
  STAGEK2(0, 0);
  if (nch > 1) STAGEK2(1, 1);
  cur = 0;
  for (int ci = 0; ci < nch; ci++) {
    if (ci + 1 < nch) WAIT_VM(4); else WAIT_VM(0);
    BAR();
    f32x4 acc[2][4] = {};
#pragma unroll
    for (int ks = 0; ks < 2; ks++) {
#pragma unroll
      for (int j = 0; j < 4; j++) {
        int br = wn * 64 + j * 16 + l15;
        int off = br * 64 + (((ks * 4 + l4) ^ (br & 7)) * 8);
        bf16x8 bh_ = *reinterpret_cast<const bf16x8*>(&Khs[cur][off]);
        bf16x8 bl_ = *reinterpret_cast<const bf16x8*>(&Kls[cur][off]);
#pragma unroll
        for (int i = 0; i < 2; i++) {
          acc[i][j] = __builtin_amdgcn_mfma_f32_16x16x32_bf16(aq[ks][i], bh_, acc[i][j], 0, 0, 0);
          acc[i][j] = __builtin_amdgcn_mfma_f32_16x16x32_bf16(aq[ks][i], bl_, acc[i][j], 0, 0, 0);
          acc[i][j] = __builtin_amdgcn_mfma_f32_16x16x32_bf16(aql[ks][i], bh_, acc[i][j], 0, 0, 0);
        }
      }
    }
    const bool diag = (ci == rt);
    float cp[4];
#pragma unroll
    for (int j = 0; j < 4; j++) cp[j] = 0.f;
#pragma unroll
    for (int i = 0; i < 2; i++)
#pragma unroll
      for (int r = 0; r < 4; r++) {
        int row = row0 + wm * 32 + i * 16 + l4 * 4 + r;
        float il = invl[i][r];
#pragma unroll
        for (int j = 0; j < 4; j++) {
          int key = ci * 128 + wn * 64 + j * 16 + l15;
          float p = __expf(acc[i][j][r] * QSCALE) * il;
          if (diag && key > row) p = 0.f;
          cp[j] += p;
        }
      }
#pragma unroll
    for (int j = 0; j < 4; j++) {
      float v = cp[j];
      v += __shfl_xor(v, 16); v += __shfl_xor(v, 32);
      cp[j] = v;
    }
    WAIT_LGKM0;
    BAR();   // Khs/Kls[cur] reads done; prev iter's csw reads done
    if (ci + 2 < nch) STAGEK2(cur, ci + 2);
    if (l4 == 0) {
#pragma unroll
      for (int j = 0; j < 4; j++)
        csw[w * 128 + wn * 64 + j * 16 + l15] = cp[j];
    }
    WAIT_LGKM0;
    BAR();   // csw visible (DS-only fence; prefetch stays in flight)
    if (tid < 128) {
      int wnc = tid >> 6;
      float s = csw[(0 * 2 + wnc) * 128 + tid] + csw[(1 * 2 + wnc) * 128 + tid] +
                csw[(2 * 2 + wnc) * 128 + tid] + csw[(3 * 2 + wnc) * 128 + tid];
      part[((size_t)(bh * 16 + slab)) * 2048 + ci * 128 + tid] = s;   // first touch
    }
    cur ^= 1;
  }
}

// ---------------- Top-K select + gather (K f16, V f16-transposed) ----------------
__global__ __launch_bounds__(256) void topk_gather_kernel(
    const float* __restrict__ part,
    const unsigned short* __restrict__ Kh, const unsigned short* __restrict__ Kl,
    const float* __restrict__ V,
    unsigned short* __restrict__ Kf, unsigned short* __restrict__ Vt)
{
  const int bh = blockIdx.x, tid = threadIdx.x;
  const int lane = tid & 63, w = tid >> 6;
  __shared__ int redi[4];
  __shared__ int stot;
  __shared__ int base[256];
  __shared__ int idxb[KKEEP];
  unsigned u[8];
#pragma unroll
  for (int k = 0; k < 8; k++) {
    int e = tid * 8 + k;
    float s = 0.f;
#pragma unroll
    for (int p = 0; p < 16; p++) {
      int rtp = (p & 1) ? 15 - (p >> 1) : (p >> 1);
      if (e < (rtp + 1) * 128) s += part[((size_t)(bh * 16 + p)) * 2048 + e];
    }
    float v = (e >= TT - REC) ? 3.0e3f : s;
    u[k] = __float_as_uint(v);
  }
  unsigned lo = 0u, hi = 0x7f800000u;
  for (int it = 0; it < 31; it++) {
    unsigned mid = lo + ((hi - lo + 1) >> 1);
    int c = 0;
#pragma unroll
    for (int k = 0; k < 8; k++) c += (u[k] >= mid) ? 1 : 0;
#pragma unroll
    for (int off = 1; off <= 32; off <<= 1) c += __shfl_xor(c, off);
    if (lane == 0) redi[w] = c;
    __syncthreads();
    int tot = redi[0] + redi[1] + redi[2] + redi[3];
    if (tot >= KKEEP) lo = mid; else hi = mid - 1;
    __syncthreads();
  }
  const unsigned vstar = lo;
  int cgt = 0, ceq = 0;
#pragma unroll
  for (int k = 0; k < 8; k++) { cgt += (u[k] > vstar) ? 1 : 0; ceq += (u[k] == vstar) ? 1 : 0; }
  base[tid] = cgt; __syncthreads();
  if (tid == 0) {
    int run = 0;
    for (int i = 0; i < 256; i++) { int t = base[i]; base[i] = run; run += t; }
    stot = run;
  }
  __syncthreads();
  int off1 = base[tid];
#pragma unroll
  for (int k = 0; k < 8; k++)
    if (u[k] > vstar) idxb[off1++] = tid * 8 + k;
  __syncthreads();
  base[tid] = ceq; __syncthreads();
  if (tid == 0) {
    int run = 0;
    for (int i = 0; i < 256; i++) { int t = base[i]; base[i] = run; run += t; }
  }
  __syncthreads();
  int off2 = stot + base[tid];
#pragma unroll
  for (int k = 0; k < 8; k++)
    if (u[k] == vstar) { if (off2 < KKEEP) idxb[off2] = tid * 8 + k; off2++; }
  __syncthreads();
  // K -> f16 plane [bh][KPAD][64], zero-padded
  for (int f = tid; f < KPAD * 8; f += 256) {
    int kk = f >> 3, c8 = f & 7;
    union { _Float16 h[8]; uint4 v; } o;
#pragma unroll
    for (int j = 0; j < 8; j++) o.h[j] = (_Float16)0.f;
    if (kk < KKEEP) {
      int sr = idxb[kk];
      bf16x8 hv = *reinterpret_cast<const bf16x8*>(&Kh[((size_t)(bh * TT + sr)) * DD + c8 * 8]);
      bf16x8 lv = *reinterpret_cast<const bf16x8*>(&Kl[((size_t)(bh * TT + sr)) * DD + c8 * 8]);
#pragma unroll
      for (int j = 0; j < 8; j++)
        o.h[j] = (_Float16)(bf_up((unsigned short)hv[j]) + bf_up((unsigned short)lv[j]));
    }
    *reinterpret_cast<uint4*>(&Kf[((size_t)(bh * KPAD) + kk) * DD + c8 * 8]) = o.v;
  }
  // V -> f16 transposed plane [bh][64][KPAD], zero-padded
  for (int f = tid; f < KPAD * 8; f += 256) {
    int kk = f >> 3, d8 = f & 7;
    float vv[8];
#pragma unroll
    for (int j = 0; j < 8; j++) vv[j] = 0.f;
    if (kk < KKEEP) {
      int sr = idxb[kk];
      float4 a = *reinterpret_cast<const float4*>(&V[((size_t)(bh * TT + sr)) * DD + d8 * 8]);
      float4 b = *reinterpret_cast<const float4*>(&V[((size_t)(bh * TT + sr)) * DD + d8 * 8 + 4]);
      vv[0] = a.x; vv[1] = a.y; vv[2] = a.z; vv[3] = a.w;
      vv[4] = b.x; vv[5] = b.y; vv[6] = b.z; vv[7] = b.w;
    }
#pragma unroll
    for (int j = 0; j < 8; j++) {
      union { _Float16 h; unsigned short s; } t;
      t.h = (_Float16)vv[j];
      Vt[((size_t)(bh * DD) + d8 * 8 + j) * KPAD + kk] = t.s;
    }
  }
}

// ---------------- Pass-2 attention: f16 MFMA, counted pipeline ----------------
__global__ __launch_bounds__(256) void attn4_kernel(
    const unsigned short* __restrict__ Qh, const unsigned short* __restrict__ Ql,
    const unsigned short* __restrict__ Kf, const unsigned short* __restrict__ Vt,
    unsigned short* __restrict__ AOh, unsigned short* __restrict__ AOl)
{
  const int rt = blockIdx.y, bh = blockIdx.x;
  const int tid = threadIdx.x;
  const int w = tid >> 6, lane = tid & 63;
  const int l15 = lane & 15, l4 = lane >> 4;
  __shared__ __align__(16) unsigned short Qs[64 * 64];
  __shared__ __align__(16) unsigned short Ks[2][64 * 64];
  __shared__ __align__(16) unsigned short Vs[2][64 * 64];
  __shared__ float LDSo[4][64][16];
  const int row0 = rt * 64;

  int srow[2], skb[2], slds[2];
#pragma unroll
  for (int s = 0; s < 2; s++) {
    int seg = w * 2 + s;
    int r = seg * 8 + (lane >> 3);
    int k8 = lane & 7;
    srow[s] = r; skb[s] = k8 ^ (r & 7); slds[s] = seg * 512;
  }
  auto STAGEA = [&](int bb, int ci) {
#pragma unroll
    for (int s = 0; s < 2; s++) {
      glds16(&Kf[((size_t)(bh * KPAD) + ci * 64 + srow[s]) * DD + skb[s] * 8], &Ks[bb][slds[s]]);
      glds16(&Vt[((size_t)(bh * DD) + srow[s]) * KPAD + ci * 64 + skb[s] * 8], &Vs[bb][slds[s]]);
    }
  };

  // stage Q (f16) from split-bf16 planes (plain ds stores)
#pragma unroll
  for (int it = 0; it < 2; it++) {
    int idx = it * 256 + tid;
    int r = idx >> 3, k8 = idx & 7;
    size_t ga = ((size_t)(bh * TT + row0 + r)) * DD + k8 * 8;
    bf16x8 hv = *reinterpret_cast<const bf16x8*>(&Qh[ga]);
    bf16x8 lv = *reinterpret_cast<const bf16x8*>(&Ql[ga]);
    union { _Float16 h[8]; uint4 v; } q16;
#pragma unroll
    for (int j = 0; j < 8; j++)
      q16.h[j] = (_Float16)(bf_up((unsigned short)hv[j]) + bf_up((unsigned short)lv[j]));
    *reinterpret_cast<uint4*>(&Qs[r * 64 + ((k8 ^ (r & 7)) * 8)]) = q16.v;
  }
  STAGEA(0, 0);
  STAGEA(1, 1);
  WAIT_LGKM0;    // Q ds-writes visible (prefetch stays in flight)
  BAR();
  // hoist Q B-fragments (wave's 16 q rows)
  f16x8 bq[2];
#pragma unroll
  for (int ks = 0; ks < 2; ks++) {
    int br = w * 16 + l15;
    bq[ks] = *reinterpret_cast<const f16x8*>(&Qs[br * 64 + (((ks * 4 + l4) ^ (br & 7)) * 8)]);
  }

  f32x4 acc_o[4] = {};
  float rsum = 0.f;
  int cur = 0;

  for (int ci = 0; ci < 7; ci++) {
    if (ci + 1 < 7) WAIT_VM(4); else WAIT_VM(0);
    BAR();
    // QK^T swapped: C[key][q]
    f32x4 accs[4] = {};
#pragma unroll
    for (int ks = 0; ks < 2; ks++) {
#pragma unroll
      for (int i = 0; i < 4; i++) {
        int kr = i * 16 + l15;
        f16x8 af = *reinterpret_cast<const f16x8*>(&Ks[cur][kr * 64 + (((ks * 4 + l4) ^ (kr & 7)) * 8)]);
        accs[i] = __builtin_amdgcn_mfma_f32_16x16x32_f16(af, bq[ks], accs[i], 0, 0, 0);
      }
    }
    float p[4][4];
#pragma unroll
    for (int i = 0; i < 4; i++)
#pragma unroll
      for (int r = 0; r < 4; r++) {
        int gk = ci * 64 + i * 16 + l4 * 4 + r;
        float pp = __expf(accs[i][r] * QSCALE);
        if (gk >= KKEEP) pp = 0.f;
        p[i][r] = pp;
        rsum += pp;
      }
    unsigned pkU[4][2];
#pragma unroll
    for (int i = 0; i < 4; i++) {
      pkU[i][0] = pkf16(p[i][0], p[i][1]);
      pkU[i][1] = pkf16(p[i][2], p[i][3]);
    }
#pragma unroll
    for (int ks = 0; ks < 2; ks++) {
      union { f16x8 h; unsigned u[4]; } bp;
#pragma unroll
      for (int wp = 0; wp < 4; wp++) {
        int src = ((l4 & 1) * 2 + (wp >> 1)) * 16 + l15;
        unsigned v0 = (unsigned)__shfl((int)pkU[ks * 2][wp & 1], src);
        unsigned v1 = (unsigned)__shfl((int)pkU[ks * 2 + 1][wp & 1], src);
        bp.u[wp] = (l4 & 2) ? v1 : v0;
      }
#pragma unroll
      for (int i = 0; i < 4; i++) {
        int dr = i * 16 + l15;
        f16x8 av = *reinterpret_cast<const f16x8*>(&Vs[cur][dr * 64 + (((ks * 4 + l4) ^ (dr & 7)) * 8)]);
        acc_o[i] = __builtin_amdgcn_mfma_f32_16x16x32_f16(av, bp.h, acc_o[i], 0, 0, 0);
      }
    }
    WAIT_LGKM0;
    BAR();
    if (ci + 2 < 7) STAGEA(cur, ci + 2);
    cur ^= 1;
  }
  // normalize and transpose via LDS (outstanding vmcnt == 0 here)
  rsum += __shfl_xor(rsum, 16);
  rsum += __shfl_xor(rsum, 32);
  float inv = 1.0f / rsum;
#pragma unroll
  for (int i = 0; i < 4; i++)
#pragma unroll
    for (int r = 0; r < 4; r++)
      LDSo[w][i * 16 + l4 * 4 + r][l15] = acc_o[i][r] * inv;
  __syncthreads();
  const int b = bh >> 4, h = bh & 15;
#pragma unroll
  for (int uu = 0; uu < 2; uu++) {
    int u = uu * 64 + lane;
    int q = u >> 3, dc = u & 7;
    int row = row0 + w * 16 + q;
    union { unsigned short s[8]; uint4 v; } sh, sl;
#pragma unroll
    for (int j = 0; j < 8; j++) {
      float v = LDSo[w][dc * 8 + j][q];
      unsigned short hh = bf_rn(v);
      sh.s[j] = hh;
      sl.s[j] = bf_rn(v - bf_up(hh));
    }
    size_t addr = ((size_t)(b * TT + row)) * EE + h * DD + dc * 8;
    *reinterpret_cast<uint4*>(&AOh[addr]) = sh.v;
    *reinterpret_cast<uint4*>(&AOl[addr]) = sl.v;
  }
}

extern "C" void kernel_launch(void* const* d_in, const int* in_sizes, int n_in,
                              void* d_out, int out_size, void* d_ws, size_t ws_size,
                              hipStream_t stream)
{
  const float* x     = (const float*)d_in[0];
  const float* Wattn = (const float*)d_in[1];
  const float* Wproj = (const float*)d_in[2];
  float* out = (float*)d_out;
  float* ws  = (float*)d_ws;

  const size_t SZQ = (size_t)NBH * TT * DD;            // 4,194,304 elements
  const size_t SZK = (size_t)NBH * KPAD * DD;          // 917,504
  float* Vb   = ws;                                    // f32 V
  float* part = Vb + SZQ;                              // 32*16*2048 = 1,048,576 f
  unsigned short* Kf  = (unsigned short*)(part + (size_t)NBH * 16 * TT);
  unsigned short* Vt  = Kf + SZK;
  unsigned short* Qhp = Vt + SZK;
  unsigned short* Qlp = Qhp + SZQ;
  unsigned short* Khp = Qlp + SZQ;
  unsigned short* Klp = Khp + SZQ;
  unsigned short* xh  = Klp + SZQ;                     // x splits (dead after QKV)
  unsigned short* xl  = xh + (size_t)4096 * 1024;
  unsigned short* Wh  = xl + (size_t)4096 * 1024;      // W_attn splits
  unsigned short* Wl  = Wh + (size_t)3072 * 1024;
  unsigned short* AOh = xh;                            // alias
  unsigned short* AOl = xl;
  unsigned short* Ph  = Wh;                            // alias (after QKV GEMMs)
  unsigned short* Pl  = Ph + (size_t)1024 * 1024;

  const size_t needB =
      ((size_t)SZQ + (size_t)NBH * 16 * TT) * 4 +
      ((size_t)2 * SZK + (size_t)4 * SZQ + (size_t)2 * 4096 * 1024 + (size_t)2 * 3072 * 1024) * 2;
  if (ws_size < needB) return;   // ~87.6 MB

  // 0) split x + W_attn into bf16 hi/lo planes (merged launch)
  split2_kernel<<<1024, 256, 0, stream>>>(x, Wattn, xh, xl, Wh, Wl);
  // 1) QKV projection: Q/K columns (3-product) and V columns (1-product)
  gemm_pipe<false, 1><<<dim3(16, 32), 256, 0, stream>>>(xh, xl, Wh, Wl, nullptr,
      Qhp, Qlp, Khp, Klp, nullptr, 4096, 3072, 1024, 0);
  gemm_pipe<true, 1><<<dim3(8, 32), 256, 0, stream>>>(xh, xl, Wh, Wl, nullptr,
      nullptr, nullptr, nullptr, nullptr, Vb, 4096, 3072, 1024, 2048);
  // 1b) split W_proj (aliases W_attn splits; stream-ordered after QKV GEMMs)
  split_kernel<<<256, 256, 0, stream>>>(Wproj, Ph, Pl, 1024 * 1024);
  // 2) causal softmax column sums (512 blocks, 2/CU, private slabs)
  importance5_kernel<<<dim3(NBH, 8, 2), 512, 0, stream>>>(Qhp, Qlp, Khp, Klp, part);
  // 3) exact top-391 + gather
  topk_gather_kernel<<<NBH, 256, 0, stream>>>(part, Khp, Klp, Vb, Kf, Vt);
  // 4) pruned-key attention (counted pipeline)
  attn4_kernel<<<dim3(NBH, 32), 256, 0, stream>>>(Qhp, Qlp, Kf, Vt, AOh, AOl);
  // 5) output projection
  gemm_pipe<false, 0><<<dim3(8, 32), 256, 0, stream>>>(AOh, AOl, Ph, Pl, out,
      nullptr, nullptr, nullptr, nullptr, nullptr, 4096, 1024, 1024, 0);
}